// Round 7
// baseline (332.550 us; speedup 1.0000x reference)
//
#include <hip/hip_runtime.h>
#include <hip/hip_bf16.h>
#include <stdint.h>
#include <stddef.h>

typedef __attribute__((ext_vector_type(8))) short short8;
typedef __attribute__((ext_vector_type(4))) float f32x4;
typedef unsigned short ushort_t;

#define NHEADS 16
#define HD 32
#define NQ 740
#define NB 16
#define MROWS (NB*NQ)       // 11840
#define CD 512
#define KDIM 512
#define VSTRIDE 768         // v^T row stride
#define NQT 48              // padded q-tile slots for bias
#define PTS 40              // P[q][key] stride in bf16 (32 keys + 8 pad); 80B rows: b128 reads 16B-aligned
#define QS2 0.2550400865f   // hd^-0.5 * log2(e)
#define LOG2E 1.4426950409f
#define NEG_BIG -43000.0f   // log2e-scaled mask; v_exp_f32 flushes to 0

static __device__ __forceinline__ void gld_lds16(const void* g, void* l) {
    __builtin_amdgcn_global_load_lds((const __attribute__((address_space(1))) void*)g,
                                     (__attribute__((address_space(3))) void*)l,
                                     16, 0, 0);
}

static __device__ __forceinline__ float ldf(const void* p, int i, int fl) {
    return fl ? ((const float*)p)[i] : (float)((const __hip_bfloat16*)p)[i];
}
static __device__ __forceinline__ ushort_t f2bf(float f) {
    __hip_bfloat16 h(f);
    return *reinterpret_cast<ushort_t*>(&h);
}
static __device__ __forceinline__ float fexp2(float x) {
#if __has_builtin(__builtin_amdgcn_exp2f)
    return __builtin_amdgcn_exp2f(x);
#else
    return exp2f(x);
#endif
}
// unpack 4 consecutive bf16 -> f32x4 (for MFMA acc init from bias)
static __device__ __forceinline__ f32x4 bias4(const __hip_bfloat16* p) {
    uint2 u = *(const uint2*)(const void*)p;
    f32x4 c;
    c[0] = __uint_as_float(u.x << 16);
    c[1] = __uint_as_float(u.x & 0xFFFF0000u);
    c[2] = __uint_as_float(u.y << 16);
    c[3] = __uint_as_float(u.y & 0xFFFF0000u);
    return c;
}
// pack f32x4 -> 4 bf16 (RNE, packed HW cvt), single 8B LDS store
static __device__ __forceinline__ void pkstore(__hip_bfloat16* dst, f32x4 c) {
    __hip_bfloat162* d = (__hip_bfloat162*)dst;
    d[0] = __float22bfloat162_rn(make_float2(c[0], c[1]));
    d[1] = __float22bfloat162_rn(make_float2(c[2], c[3]));
}
static __device__ __forceinline__ uint2 pk4(float a, float b, float c, float d) {
    __hip_bfloat162 p01 = __float22bfloat162_rn(make_float2(a, b));
    __hip_bfloat162 p23 = __float22bfloat162_rn(make_float2(c, d));
    uint2 u;
    u.x = *reinterpret_cast<unsigned int*>(&p01);
    u.y = *reinterpret_cast<unsigned int*>(&p23);
    return u;
}

// ------------- dtype sniff: fp32 arrays have uniform low-16 mantissa bits ----
__global__ __launch_bounds__(64) void sniff_k(const unsigned int* __restrict__ w,
                                              int* __restrict__ flag) {
    int cnt = 0;
    for (int i = threadIdx.x; i < 1024; i += 64) {
        unsigned int e = (w[i] >> 7) & 0xFFu;
        cnt += (e > 135u) ? 1 : 0;
    }
    #pragma unroll
    for (int d = 1; d < 64; d <<= 1) cnt += __shfl_xor(cnt, d);
    if (threadIdx.x == 0) *flag = (cnt > 16) ? 1 : 0;
}

// ------------- x normalization: fp32->bf16 (vectorized) or bf16 copy ---------
__global__ __launch_bounds__(256) void convx_k(const void* __restrict__ src,
                                               ushort4* __restrict__ dst,
                                               int nquads, const int* __restrict__ flag) {
    int i = blockIdx.x * 256 + threadIdx.x;
    if (i >= nquads) return;
    if (*flag) {
        float4 v = ((const float4*)src)[i];
        ushort4 o;
        o.x = f2bf(v.x); o.y = f2bf(v.y); o.z = f2bf(v.z); o.w = f2bf(v.w);
        dst[i] = o;
    } else {
        dst[i] = ((const ushort4*)src)[i];
    }
}

// ---------------- transpose + convert (for B^T weight layouts) ----------------
__global__ __launch_bounds__(256) void transpose_k(const void* __restrict__ src,
                                                   __hip_bfloat16* __restrict__ dst,
                                                   int R, int C, const int* __restrict__ flag) {
    __shared__ __hip_bfloat16 tile[32][33];
    const int fl = *flag;
    int bx = blockIdx.x * 32;   // col base in src
    int by = blockIdx.y * 32;   // row base in src
    int tx = threadIdx.x;
    for (int r = threadIdx.y; r < 32; r += 8)
        tile[r][tx] = __hip_bfloat16(ldf(src, (by + r) * C + bx + tx, fl));
    __syncthreads();
    for (int r = threadIdx.y; r < 32; r += 8)
        dst[(size_t)(bx + r) * R + by + tx] = tile[tx][r];
}

// ------ bias * log2e, row-major per q-tile: [hh][qt(48)][q 16][key 768] bf16 --
// (matches S^T C-layout acc init: lane q=col, 4 consecutive keys per reg group)
__global__ __launch_bounds__(256) void biasB_k(
    const void* __restrict__ btT,    // bias_table_target [1849][16]
    const void* __restrict__ btt,    // bias_table_temp   [961][16]
    const void* __restrict__ ttab,   // temp_target_table [16][484]
    const void* __restrict__ tgtab,  // target_temp_table [16][256]
    const void* __restrict__ ttln,   // temp_target_line  [16][256]
    const void* __restrict__ tgln,   // target_temp_line  [16][484]
    __hip_bfloat16* __restrict__ biasB, const int* __restrict__ flag) {
    const int fl = *flag;
    const int blk = blockIdx.x;          // hh*48 + qt
    const int hh = blk / NQT;
    const int qt = blk - hh * NQT;
    for (int idx = threadIdx.x; idx < 16 * 192; idx += 256) {   // 192 quads/row
        const int q = idx / 192;
        const int c0 = (idx - q * 192) * 4;
        int i = qt * 16 + q; if (i > NQ - 1) i = NQ - 1;
        ushort4 o;
        ushort_t* op = (ushort_t*)&o;
        #pragma unroll
        for (int r = 0; r < 4; ++r) {
            int c = c0 + r;
            float v;
            if (c >= NQ) {
                v = NEG_BIG;
            } else if (i < 256) {
                if (c < 256) {
                    int t = ((i >> 4) - (c >> 4) + 15) * 31 + ((i & 15) - (c & 15) + 15);
                    v = ldf(btt, t * 16 + hh, fl) * LOG2E;
                } else {
                    v = (ldf(tgtab, hh * 256 + i, fl) + ldf(tgln, hh * 484 + (c - 256), fl)) * LOG2E;
                }
            } else {
                int ii = i - 256;
                if (c < 256) {
                    v = (ldf(ttab, hh * 484 + ii, fl) + ldf(ttln, hh * 256 + c, fl)) * LOG2E;
                } else {
                    int jj = c - 256;
                    int a = ii / 22, b2 = ii - a * 22;
                    int a2 = jj / 22, b3 = jj - a2 * 22;
                    int t = (a - a2 + 21) * 43 + (b2 - b3 + 21);
                    v = ldf(btT, t * 16 + hh, fl) * LOG2E;
                }
            }
            op[r] = f2bf(v);
        }
        ((ushort4*)biasB)[(size_t)blk * 16 * 192 + q * 192 + (c0 >> 2)] = o;
    }
}

// ------- qkv GEMM: 256x128 tile, 4 waves (each 64 rows x ALL 128 cols) -------
__global__ __launch_bounds__(256) void gemm_qkv(
    const __hip_bfloat16* __restrict__ A,
    const __hip_bfloat16* __restrict__ Bt,
    const void* __restrict__ biasv,
    __hip_bfloat16* __restrict__ Qw,
    __hip_bfloat16* __restrict__ Kw,
    __hip_bfloat16* __restrict__ Vtw,
    const int* __restrict__ flag) {
    __shared__ __attribute__((aligned(16))) short sA[256 * 32];   // 16 KB
    __shared__ __attribute__((aligned(16))) short sB[128 * 32];   // 8 KB
    const int tid = threadIdx.x;
    const int lane = tid & 63;
    const int wv = tid >> 6;             // 0..3: 64-row group
    const int lr = lane & 15, kc = lane >> 4;
    const int m0 = blockIdx.x * 256;
    const int n0 = blockIdx.y * 128;
    const int fl = *flag;
    const int M = MROWS;

    f32x4 acc[4][8] = {};

    for (int k0 = 0; k0 < KDIM; k0 += 32) {
        #pragma unroll
        for (int it = 0; it < 6; ++it) {
            int idx = it * 256 + tid;            // 16B unit index, 0..1535
            if (idx < 1024) {                    // A: 256 rows x 4 units
                int r = idx >> 2, c = idx & 3;
                int gr = m0 + r; if (gr > M - 1) gr = M - 1;
                gld_lds16(A + (size_t)gr * KDIM + k0 + c * 8, (char*)sA + idx * 16);
            } else {                             // B: 128 rows x 4 units
                int u = idx - 1024;
                int r = u >> 2, c = u & 3;
                gld_lds16(Bt + (size_t)(n0 + r) * KDIM + k0 + c * 8, (char*)sB + u * 16);
            }
        }
        __syncthreads();
        short8 af[4], bfr[8];
        #pragma unroll
        for (int t = 0; t < 4; ++t)
            af[t] = *(const short8*)&sA[(wv * 64 + t * 16 + lr) * 32 + kc * 8];
        #pragma unroll
        for (int t = 0; t < 8; ++t)
            bfr[t] = *(const short8*)&sB[(t * 16 + lr) * 32 + kc * 8];
        #pragma unroll
        for (int i = 0; i < 4; ++i)
            #pragma unroll
            for (int j = 0; j < 8; ++j)
                acc[i][j] = __builtin_amdgcn_mfma_f32_16x16x32_bf16(af[i], bfr[j], acc[i][j], 0, 0, 0);
        __syncthreads();
    }

    #pragma unroll
    for (int j = 0; j < 8; ++j) {
        int gn = n0 + j * 16 + lr;
        float bv = ldf(biasv, gn, fl);
        int s = gn >> 9;                  // 0:q 1:k 2:v
        int hh = (gn >> 5) & 15;
        int d = gn & 31;
        #pragma unroll
        for (int i = 0; i < 4; ++i) {
            int gm0 = m0 + wv * 64 + i * 16 + kc * 4;   // %4==0; group all-in or all-out
            if (gm0 >= M) continue;
            int b = gm0 / NQ;
            int nn = gm0 - b * NQ;                      // %4==0, no b-straddle in group
            size_t bh = (size_t)(b * 16 + hh);
            if (s == 2) {
                uint2 u = pk4(acc[i][j][0] + bv, acc[i][j][1] + bv,
                              acc[i][j][2] + bv, acc[i][j][3] + bv);
                *(uint2*)(void*)(Vtw + (bh * HD + d) * VSTRIDE + nn) = u;
            } else if (s == 0) {
                #pragma unroll
                for (int r = 0; r < 4; ++r)
                    Qw[(bh * NQ + nn + r) * HD + d] = __hip_bfloat16((acc[i][j][r] + bv) * QS2);
            } else {
                #pragma unroll
                for (int r = 0; r < 4; ++r)
                    Kw[(bh * NQ + nn + r) * HD + d] = __hip_bfloat16(acc[i][j][r] + bv);
            }
        }
    }
}

// ---------------- m97-style 128x128 bf16 GEMM (proj): Out = A @ Bt^T + bias ---
__global__ __launch_bounds__(256) void gemm_bt(
    const __hip_bfloat16* __restrict__ A,
    const __hip_bfloat16* __restrict__ Bt,
    const void* __restrict__ biasv,
    int M,
    __hip_bfloat16* __restrict__ Out,
    float* __restrict__ OutF,
    const int* __restrict__ flag) {
    __shared__ __attribute__((aligned(16))) short sA[128 * 32];
    __shared__ __attribute__((aligned(16))) short sB[128 * 32];
    const int tid = threadIdx.x;
    const int lane = tid & 63;
    const int wv = tid >> 6;
    const int wr = wv >> 1, wc = wv & 1;
    const int lr = lane & 15, kc = lane >> 4;
    const int m0 = blockIdx.x * 128;
    const int n0 = blockIdx.y * 128;
    const int fl = *flag;

    f32x4 acc[4][4] = {};

    for (int k0 = 0; k0 < KDIM; k0 += 32) {
        #pragma unroll
        for (int it = 0; it < 2; ++it) {
            int idx = it * 256 + tid;           // 16-byte unit index
            int r = idx >> 2;
            int c = idx & 3;
            int gr = m0 + r; if (gr > M - 1) gr = M - 1;
            gld_lds16(A + (size_t)gr * KDIM + k0 + c * 8, (char*)sA + idx * 16);
            gld_lds16(Bt + (size_t)(n0 + r) * KDIM + k0 + c * 8, (char*)sB + idx * 16);
        }
        __syncthreads();
        short8 af[4], bfr[4];
        #pragma unroll
        for (int t = 0; t < 4; ++t)
            af[t] = *(const short8*)&sA[(wr * 64 + t * 16 + lr) * 32 + kc * 8];
        #pragma unroll
        for (int t = 0; t < 4; ++t)
            bfr[t] = *(const short8*)&sB[(wc * 64 + t * 16 + lr) * 32 + kc * 8];
        #pragma unroll
        for (int i = 0; i < 4; ++i)
            #pragma unroll
            for (int j = 0; j < 4; ++j)
                acc[i][j] = __builtin_amdgcn_mfma_f32_16x16x32_bf16(af[i], bfr[j], acc[i][j], 0, 0, 0);
        __syncthreads();
    }

    #pragma unroll
    for (int i = 0; i < 4; ++i) {
        #pragma unroll
        for (int j = 0; j < 4; ++j) {
            int gn = n0 + wc * 64 + j * 16 + lr;
            float bv = ldf(biasv, gn, fl);
            #pragma unroll
            for (int r = 0; r < 4; ++r) {
                int gm = m0 + wr * 64 + i * 16 + kc * 4 + r;
                if (gm < M) {
                    float v = acc[i][j][r] + bv;
                    if (fl) OutF[(size_t)gm * CD + gn] = v;
                    else    Out[(size_t)gm * CD + gn] = __hip_bfloat16(v);
                }
            }
        }
    }
}

// ---- fused attention v4: S^T MFMA (swapped operands) -> packed LDS both ways -
// c = mfma(kf, qf, bias): D[row=key][col=q] -> lane's 4 regs = 4 consecutive
// keys at fixed q -> b64 writes into P[q][key]; PV A-frag = 8 consecutive keys
// at fixed q -> b128 reads. LDS ops/K-step: 20 -> 6. All 24 waves/CU resident
// via __launch_bounds__(256,6).
__global__ __launch_bounds__(256, 6) void attn_k(
    const __hip_bfloat16* __restrict__ Qw,
    const __hip_bfloat16* __restrict__ Kw,
    const __hip_bfloat16* __restrict__ Vtw,
    const __hip_bfloat16* __restrict__ biasB,
    __hip_bfloat16* __restrict__ AO) {
    __shared__ __attribute__((aligned(16))) __hip_bfloat16 Pt[4][32 * PTS];

    const int tid = threadIdx.x;
    const int wv = tid >> 6;
    const int pair = blockIdx.x * 4 + wv;    // 0..23 exactly
    const int bh = blockIdx.y;               // b*16 + h
    const int hh = bh & 15;
    const int b = bh >> 4;
    const int q0 = pair * 32;
    const int lane = tid & 63;
    const int lr = lane & 15, kc = lane >> 4;

    const __hip_bfloat16* Qb = Qw + (size_t)bh * NQ * HD;
    const __hip_bfloat16* Kb = Kw + (size_t)bh * NQ * HD;
    const __hip_bfloat16* Vb = Vtw + (size_t)bh * HD * VSTRIDE;
    __hip_bfloat16* Pw = &Pt[wv][0];

    int qrA = q0 + lr;      if (qrA > NQ - 1) qrA = NQ - 1;
    int qrB = q0 + 16 + lr; if (qrB > NQ - 1) qrB = NQ - 1;
    short8 qfA = *(const short8*)(const void*)(Qb + qrA * HD + kc * 8);
    short8 qfB = *(const short8*)(const void*)(Qb + qrB * HD + kc * 8);

    short8 onesf;
    {
        short s1 = (lr == 0) ? (short)0x3F80 : (short)0;
        #pragma unroll
        for (int j = 0; j < 8; ++j) onesf[j] = s1;
    }

    // bias rows for this pair's two 16-q tiles: [q 16][key 768] each
    const __hip_bfloat16* bt0 = biasB + (size_t)(hh * NQT + 2 * pair) * 16 * 768;
    const __hip_bfloat16* bt1 = bt0 + 16 * 768;

    f32x4 oa0 = {}, ob0 = {}, ol0 = {};
    f32x4 oa1 = {}, ob1 = {}, ol1 = {};

    for (int ks = 0; ks < 24; ++ks) {
        const int k0 = ks * 32;
        int kr0 = k0 + lr;      if (kr0 > NQ - 1) kr0 = NQ - 1;
        int kr1 = k0 + 16 + lr; if (kr1 > NQ - 1) kr1 = NQ - 1;
        short8 kf0 = *(const short8*)(const void*)(Kb + kr0 * HD + kc * 8);
        short8 kf1 = *(const short8*)(const void*)(Kb + kr1 * HD + kc * 8);
        short8 vf0 = *(const short8*)(const void*)(Vb + (size_t)lr * VSTRIDE + k0 + kc * 8);
        short8 vf1 = *(const short8*)(const void*)(Vb + (size_t)(lr + 16) * VSTRIDE + k0 + kc * 8);

        // acc init: bias[q=lr][4 consecutive keys kc*4..] per tile/half
        f32x4 c0 = bias4(bt0 + lr * 768 + k0 + kc * 4);
        f32x4 c1 = bias4(bt0 + lr * 768 + k0 + 16 + kc * 4);
        f32x4 c2 = bias4(bt1 + lr * 768 + k0 + kc * 4);
        f32x4 c3 = bias4(bt1 + lr * 768 + k0 + 16 + kc * 4);

        // S^T: D[key][q]
        c0 = __builtin_amdgcn_mfma_f32_16x16x32_bf16(kf0, qfA, c0, 0, 0, 0);
        c1 = __builtin_amdgcn_mfma_f32_16x16x32_bf16(kf1, qfA, c1, 0, 0, 0);
        c2 = __builtin_amdgcn_mfma_f32_16x16x32_bf16(kf0, qfB, c2, 0, 0, 0);
        c3 = __builtin_amdgcn_mfma_f32_16x16x32_bf16(kf1, qfB, c3, 0, 0, 0);

        #pragma unroll
        for (int r = 0; r < 4; ++r) {
            c0[r] = fexp2(c0[r]); c1[r] = fexp2(c1[r]);
            c2[r] = fexp2(c2[r]); c3[r] = fexp2(c3[r]);
        }
        // P[q][key]: 4 consecutive keys per reg group -> packed b64 writes
        pkstore(Pw + lr * PTS + kc * 4, c0);
        pkstore(Pw + lr * PTS + 16 + kc * 4, c1);
        pkstore(Pw + (16 + lr) * PTS + kc * 4, c2);
        pkstore(Pw + (16 + lr) * PTS + 16 + kc * 4, c3);
        asm volatile("" ::: "memory");
        __builtin_amdgcn_s_waitcnt(0xc07f);   // lgkmcnt(0); same-wave DS in order
        asm volatile("" ::: "memory");

        // A-frag: 8 consecutive keys at fixed q -> b128 reads
        short8 pfA = *(const short8*)(const void*)(Pw + lr * PTS + kc * 8);
        short8 pfB = *(const short8*)(const void*)(Pw + (16 + lr) * PTS + kc * 8);

        oa0 = __builtin_amdgcn_mfma_f32_16x16x32_bf16(pfA, vf0, oa0, 0, 0, 0);
        ob0 = __builtin_amdgcn_mfma_f32_16x16x32_bf16(pfA, vf1, ob0, 0, 0, 0);
        ol0 = __builtin_amdgcn_mfma_f32_16x16x32_bf16(pfA, onesf, ol0, 0, 0, 0);
        oa1 = __builtin_amdgcn_mfma_f32_16x16x32_bf16(pfB, vf0, oa1, 0, 0, 0);
        ob1 = __builtin_amdgcn_mfma_f32_16x16x32_bf16(pfB, vf1, ob1, 0, 0, 0);
        ol1 = __builtin_amdgcn_mfma_f32_16x16x32_bf16(pfB, onesf, ol1, 0, 0, 0);
    }

    #pragma unroll
    for (int r = 0; r < 4; ++r) {
        int row = kc * 4 + r;
        float lA = __shfl(ol0[r], lane & 48);
        float lB = __shfl(ol1[r], lane & 48);
        float liA = 1.0f / lA, liB = 1.0f / lB;
        int orA = q0 + row, orB = q0 + 16 + row;
        if (orA < NQ) {
            size_t base = ((size_t)b * NQ + orA) * CD + hh * HD;
            AO[base + lr]      = __hip_bfloat16(oa0[r] * liA);
            AO[base + 16 + lr] = __hip_bfloat16(ob0[r] * liA);
        }
        if (orB < NQ) {
            size_t base = ((size_t)b * NQ + orB) * CD + hh * HD;
            AO[base + lr]      = __hip_bfloat16(oa1[r] * liB);
            AO[base + 16 + lr] = __hip_bfloat16(ob1[r] * liB);
        }
    }
}

extern "C" void kernel_launch(void* const* d_in, const int* in_sizes, int n_in,
                              void* d_out, int out_size, void* d_ws, size_t ws_size,
                              hipStream_t stream) {
    char* ws = (char*)d_ws;
    size_t off = 0;
    auto carve = [&](size_t bytes) {
        char* p = ws + off;
        off += (bytes + 255) & ~(size_t)255;
        return p;
    };
    int* flagp = (int*)carve(256);
    __hip_bfloat16* Qw    = (__hip_bfloat16*)carve((size_t)256 * NQ * HD * 2);
    __hip_bfloat16* Kw    = (__hip_bfloat16*)carve((size_t)256 * NQ * HD * 2);
    __hip_bfloat16* Vtw   = (__hip_bfloat16*)carve((size_t)256 * HD * VSTRIDE * 2);
    __hip_bfloat16* WqT   = (__hip_bfloat16*)carve((size_t)1536 * 512 * 2);
    __hip_bfloat16* WpT   = (__hip_bfloat16*)carve((size_t)512 * 512 * 2);
    __hip_bfloat16* biasB = (__hip_bfloat16*)carve((size_t)16 * NQT * 16 * 768 * 2);
    __hip_bfloat16* Xb    = (__hip_bfloat16*)carve((size_t)MROWS * CD * 2);
    __hip_bfloat16* AO    = Xb;   // attn output overwrites x-staging (dead after qkv gemm)
    (void)ws_size; (void)in_sizes; (void)n_in; (void)out_size;

    sniff_k<<<dim3(1), dim3(64), 0, stream>>>((const unsigned int*)d_in[1], flagp);
    convx_k<<<dim3(5920), dim3(256), 0, stream>>>(d_in[0], (ushort4*)Xb, MROWS * CD / 4, flagp);
    transpose_k<<<dim3(48, 16), dim3(32, 8), 0, stream>>>(d_in[1], WqT, 512, 1536, flagp);
    transpose_k<<<dim3(16, 16), dim3(32, 8), 0, stream>>>(d_in[3], WpT, 512, 512, flagp);
    biasB_k<<<dim3(16 * NQT), dim3(256), 0, stream>>>(d_in[5], d_in[6], d_in[7], d_in[8],
                                                      d_in[9], d_in[10], biasB, flagp);
    gemm_qkv<<<dim3(47, 12), dim3(256), 0, stream>>>(Xb, WqT, d_in[2],
        Qw, Kw, Vtw, flagp);
    attn_k<<<dim3(6, 256), dim3(256), 0, stream>>>(Qw, Kw, Vtw, biasB, AO);
    gemm_bt<<<dim3(93, 4), dim3(256), 0, stream>>>(AO, WpT, d_in[4], MROWS,
        (__hip_bfloat16*)d_out, (float*)d_out, flagp);
}

// Round 8
// 285.108 us; speedup vs baseline: 1.1664x; 1.1664x over previous
//
#include <hip/hip_runtime.h>
#include <hip/hip_bf16.h>
#include <stdint.h>
#include <stddef.h>

typedef __attribute__((ext_vector_type(8))) short short8;
typedef __attribute__((ext_vector_type(4))) float f32x4;
typedef unsigned short ushort_t;

#define NHEADS 16
#define HD 32
#define NQ 740
#define NB 16
#define MROWS (NB*NQ)       // 11840
#define CD 512
#define KDIM 512
#define VSTRIDE 768         // v^T row stride
#define NQT 48              // padded q-tile slots for bias
#define PTS 40              // P[q][key] stride in bf16 (32 keys + 8 pad); 80B rows, b128 reads 16B-aligned
#define QS2 0.2550400865f   // hd^-0.5 * log2(e)
#define LOG2E 1.4426950409f
#define NEG_BIG -43000.0f   // log2e-scaled mask; v_exp_f32 flushes to 0

static __device__ __forceinline__ void gld_lds16(const void* g, void* l) {
    __builtin_amdgcn_global_load_lds((const __attribute__((address_space(1))) void*)g,
                                     (__attribute__((address_space(3))) void*)l,
                                     16, 0, 0);
}

static __device__ __forceinline__ float ldf(const void* p, int i, int fl) {
    return fl ? ((const float*)p)[i] : (float)((const __hip_bfloat16*)p)[i];
}
static __device__ __forceinline__ ushort_t f2bf(float f) {
    __hip_bfloat16 h(f);
    return *reinterpret_cast<ushort_t*>(&h);
}
static __device__ __forceinline__ float fexp2(float x) {
#if __has_builtin(__builtin_amdgcn_exp2f)
    return __builtin_amdgcn_exp2f(x);
#else
    return exp2f(x);
#endif
}
// unpack 4 consecutive bf16 -> f32x4 (for MFMA acc init from bias)
static __device__ __forceinline__ f32x4 bias4(const __hip_bfloat16* p) {
    uint2 u = *(const uint2*)(const void*)p;
    f32x4 c;
    c[0] = __uint_as_float(u.x << 16);
    c[1] = __uint_as_float(u.x & 0xFFFF0000u);
    c[2] = __uint_as_float(u.y << 16);
    c[3] = __uint_as_float(u.y & 0xFFFF0000u);
    return c;
}
// pack f32x4 -> 4 bf16 (RNE, packed HW cvt), single 8B LDS store
static __device__ __forceinline__ void pkstore(__hip_bfloat16* dst, f32x4 c) {
    __hip_bfloat162* d = (__hip_bfloat162*)dst;
    d[0] = __float22bfloat162_rn(make_float2(c[0], c[1]));
    d[1] = __float22bfloat162_rn(make_float2(c[2], c[3]));
}
static __device__ __forceinline__ uint2 pk4(float a, float b, float c, float d) {
    __hip_bfloat162 p01 = __float22bfloat162_rn(make_float2(a, b));
    __hip_bfloat162 p23 = __float22bfloat162_rn(make_float2(c, d));
    uint2 u;
    u.x = *reinterpret_cast<unsigned int*>(&p01);
    u.y = *reinterpret_cast<unsigned int*>(&p23);
    return u;
}

// ------------- dtype sniff: fp32 arrays have uniform low-16 mantissa bits ----
__global__ __launch_bounds__(64) void sniff_k(const unsigned int* __restrict__ w,
                                              int* __restrict__ flag) {
    int cnt = 0;
    for (int i = threadIdx.x; i < 1024; i += 64) {
        unsigned int e = (w[i] >> 7) & 0xFFu;
        cnt += (e > 135u) ? 1 : 0;
    }
    #pragma unroll
    for (int d = 1; d < 64; d <<= 1) cnt += __shfl_xor(cnt, d);
    if (threadIdx.x == 0) *flag = (cnt > 16) ? 1 : 0;
}

// ------------- x normalization: fp32->bf16 (vectorized) or bf16 copy ---------
__global__ __launch_bounds__(256) void convx_k(const void* __restrict__ src,
                                               ushort4* __restrict__ dst,
                                               int nquads, const int* __restrict__ flag) {
    int i = blockIdx.x * 256 + threadIdx.x;
    if (i >= nquads) return;
    if (*flag) {
        float4 v = ((const float4*)src)[i];
        ushort4 o;
        o.x = f2bf(v.x); o.y = f2bf(v.y); o.z = f2bf(v.z); o.w = f2bf(v.w);
        dst[i] = o;
    } else {
        dst[i] = ((const ushort4*)src)[i];
    }
}

// ---------------- transpose + convert (for B^T weight layouts) ----------------
__global__ __launch_bounds__(256) void transpose_k(const void* __restrict__ src,
                                                   __hip_bfloat16* __restrict__ dst,
                                                   int R, int C, const int* __restrict__ flag) {
    __shared__ __hip_bfloat16 tile[32][33];
    const int fl = *flag;
    int bx = blockIdx.x * 32;   // col base in src
    int by = blockIdx.y * 32;   // row base in src
    int tx = threadIdx.x;
    for (int r = threadIdx.y; r < 32; r += 8)
        tile[r][tx] = __hip_bfloat16(ldf(src, (by + r) * C + bx + tx, fl));
    __syncthreads();
    for (int r = threadIdx.y; r < 32; r += 8)
        dst[(size_t)(bx + r) * R + by + tx] = tile[tx][r];
}

// -- bias * log2e in S^T MFMA FRAGMENT order: [blk=hh*48+qt][kb 48][lane 64][4]
// Lane (lr,kc) of the S^T tile needs bias[q=qt*16+lr][key=kb*16+kc*4+r] as its
// acc-init quad -> attn load is base + lane*8B: one 512B coalesced transaction.
__global__ __launch_bounds__(256) void biasF_k(
    const void* __restrict__ btT,    // bias_table_target [1849][16]
    const void* __restrict__ btt,    // bias_table_temp   [961][16]
    const void* __restrict__ ttab,   // temp_target_table [16][484]
    const void* __restrict__ tgtab,  // target_temp_table [16][256]
    const void* __restrict__ ttln,   // temp_target_line  [16][256]
    const void* __restrict__ tgln,   // target_temp_line  [16][484]
    __hip_bfloat16* __restrict__ biasF, const int* __restrict__ flag) {
    const int fl = *flag;
    const int blk = blockIdx.x;          // hh*48 + qt
    const int hh = blk / NQT;
    const int qt = blk - hh * NQT;
    for (int idx = threadIdx.x; idx < 48 * 64; idx += 256) {
        const int kb = idx >> 6;         // 16-key half-block
        const int lane = idx & 63;
        const int lr = lane & 15, kc = lane >> 4;
        int i = qt * 16 + lr; if (i > NQ - 1) i = NQ - 1;
        ushort4 o;
        ushort_t* op = (ushort_t*)&o;
        #pragma unroll
        for (int r = 0; r < 4; ++r) {
            int c = kb * 16 + kc * 4 + r;
            float v;
            if (c >= NQ) {
                v = NEG_BIG;
            } else if (i < 256) {
                if (c < 256) {
                    int t = ((i >> 4) - (c >> 4) + 15) * 31 + ((i & 15) - (c & 15) + 15);
                    v = ldf(btt, t * 16 + hh, fl) * LOG2E;
                } else {
                    v = (ldf(tgtab, hh * 256 + i, fl) + ldf(tgln, hh * 484 + (c - 256), fl)) * LOG2E;
                }
            } else {
                int ii = i - 256;
                if (c < 256) {
                    v = (ldf(ttab, hh * 484 + ii, fl) + ldf(ttln, hh * 256 + c, fl)) * LOG2E;
                } else {
                    int jj = c - 256;
                    int a = ii / 22, b2 = ii - a * 22;
                    int a2 = jj / 22, b3 = jj - a2 * 22;
                    int t = (a - a2 + 21) * 43 + (b2 - b3 + 21);
                    v = ldf(btT, t * 16 + hh, fl) * LOG2E;
                }
            }
            op[r] = f2bf(v);
        }
        ((ushort4*)biasF)[(size_t)blk * 48 * 64 + idx] = o;
    }
}

// ------- qkv GEMM: 256x128 tile, 4 waves (each 64 rows x ALL 128 cols) -------
__global__ __launch_bounds__(256) void gemm_qkv(
    const __hip_bfloat16* __restrict__ A,
    const __hip_bfloat16* __restrict__ Bt,
    const void* __restrict__ biasv,
    __hip_bfloat16* __restrict__ Qw,
    __hip_bfloat16* __restrict__ Kw,
    __hip_bfloat16* __restrict__ Vtw,
    const int* __restrict__ flag) {
    __shared__ __attribute__((aligned(16))) short sA[256 * 32];   // 16 KB
    __shared__ __attribute__((aligned(16))) short sB[128 * 32];   // 8 KB
    const int tid = threadIdx.x;
    const int lane = tid & 63;
    const int wv = tid >> 6;             // 0..3: 64-row group
    const int lr = lane & 15, kc = lane >> 4;
    const int m0 = blockIdx.x * 256;
    const int n0 = blockIdx.y * 128;
    const int fl = *flag;
    const int M = MROWS;

    f32x4 acc[4][8] = {};

    for (int k0 = 0; k0 < KDIM; k0 += 32) {
        #pragma unroll
        for (int it = 0; it < 6; ++it) {
            int idx = it * 256 + tid;            // 16B unit index, 0..1535
            if (idx < 1024) {                    // A: 256 rows x 4 units
                int r = idx >> 2, c = idx & 3;
                int gr = m0 + r; if (gr > M - 1) gr = M - 1;
                gld_lds16(A + (size_t)gr * KDIM + k0 + c * 8, (char*)sA + idx * 16);
            } else {                             // B: 128 rows x 4 units
                int u = idx - 1024;
                int r = u >> 2, c = u & 3;
                gld_lds16(Bt + (size_t)(n0 + r) * KDIM + k0 + c * 8, (char*)sB + u * 16);
            }
        }
        __syncthreads();
        short8 af[4], bfr[8];
        #pragma unroll
        for (int t = 0; t < 4; ++t)
            af[t] = *(const short8*)&sA[(wv * 64 + t * 16 + lr) * 32 + kc * 8];
        #pragma unroll
        for (int t = 0; t < 8; ++t)
            bfr[t] = *(const short8*)&sB[(t * 16 + lr) * 32 + kc * 8];
        #pragma unroll
        for (int i = 0; i < 4; ++i)
            #pragma unroll
            for (int j = 0; j < 8; ++j)
                acc[i][j] = __builtin_amdgcn_mfma_f32_16x16x32_bf16(af[i], bfr[j], acc[i][j], 0, 0, 0);
        __syncthreads();
    }

    #pragma unroll
    for (int j = 0; j < 8; ++j) {
        int gn = n0 + j * 16 + lr;
        float bv = ldf(biasv, gn, fl);
        int s = gn >> 9;                  // 0:q 1:k 2:v
        int hh = (gn >> 5) & 15;
        int d = gn & 31;
        #pragma unroll
        for (int i = 0; i < 4; ++i) {
            int gm0 = m0 + wv * 64 + i * 16 + kc * 4;   // %4==0; group all-in or all-out
            if (gm0 >= M) continue;
            int b = gm0 / NQ;
            int nn = gm0 - b * NQ;                      // %4==0, no b-straddle in group
            size_t bh = (size_t)(b * 16 + hh);
            if (s == 2) {
                uint2 u = pk4(acc[i][j][0] + bv, acc[i][j][1] + bv,
                              acc[i][j][2] + bv, acc[i][j][3] + bv);
                *(uint2*)(void*)(Vtw + (bh * HD + d) * VSTRIDE + nn) = u;
            } else if (s == 0) {
                #pragma unroll
                for (int r = 0; r < 4; ++r)
                    Qw[(bh * NQ + nn + r) * HD + d] = __hip_bfloat16((acc[i][j][r] + bv) * QS2);
            } else {
                #pragma unroll
                for (int r = 0; r < 4; ++r)
                    Kw[(bh * NQ + nn + r) * HD + d] = __hip_bfloat16(acc[i][j][r] + bv);
            }
        }
    }
}

// ---------------- m97-style 128x128 bf16 GEMM (proj): Out = A @ Bt^T + bias ---
__global__ __launch_bounds__(256) void gemm_bt(
    const __hip_bfloat16* __restrict__ A,
    const __hip_bfloat16* __restrict__ Bt,
    const void* __restrict__ biasv,
    int M,
    __hip_bfloat16* __restrict__ Out,
    float* __restrict__ OutF,
    const int* __restrict__ flag) {
    __shared__ __attribute__((aligned(16))) short sA[128 * 32];
    __shared__ __attribute__((aligned(16))) short sB[128 * 32];
    const int tid = threadIdx.x;
    const int lane = tid & 63;
    const int wv = tid >> 6;
    const int wr = wv >> 1, wc = wv & 1;
    const int lr = lane & 15, kc = lane >> 4;
    const int m0 = blockIdx.x * 128;
    const int n0 = blockIdx.y * 128;
    const int fl = *flag;

    f32x4 acc[4][4] = {};

    for (int k0 = 0; k0 < KDIM; k0 += 32) {
        #pragma unroll
        for (int it = 0; it < 2; ++it) {
            int idx = it * 256 + tid;           // 16-byte unit index
            int r = idx >> 2;
            int c = idx & 3;
            int gr = m0 + r; if (gr > M - 1) gr = M - 1;
            gld_lds16(A + (size_t)gr * KDIM + k0 + c * 8, (char*)sA + idx * 16);
            gld_lds16(Bt + (size_t)(n0 + r) * KDIM + k0 + c * 8, (char*)sB + idx * 16);
        }
        __syncthreads();
        short8 af[4], bfr[4];
        #pragma unroll
        for (int t = 0; t < 4; ++t)
            af[t] = *(const short8*)&sA[(wr * 64 + t * 16 + lr) * 32 + kc * 8];
        #pragma unroll
        for (int t = 0; t < 4; ++t)
            bfr[t] = *(const short8*)&sB[(wc * 64 + t * 16 + lr) * 32 + kc * 8];
        #pragma unroll
        for (int i = 0; i < 4; ++i)
            #pragma unroll
            for (int j = 0; j < 4; ++j)
                acc[i][j] = __builtin_amdgcn_mfma_f32_16x16x32_bf16(af[i], bfr[j], acc[i][j], 0, 0, 0);
        __syncthreads();
    }

    #pragma unroll
    for (int i = 0; i < 4; ++i) {
        #pragma unroll
        for (int j = 0; j < 4; ++j) {
            int gn = n0 + wc * 64 + j * 16 + lr;
            float bv = ldf(biasv, gn, fl);
            #pragma unroll
            for (int r = 0; r < 4; ++r) {
                int gm = m0 + wr * 64 + i * 16 + kc * 4 + r;
                if (gm < M) {
                    float v = acc[i][j][r] + bv;
                    if (fl) OutF[(size_t)gm * CD + gn] = v;
                    else    Out[(size_t)gm * CD + gn] = __hip_bfloat16(v);
                }
            }
        }
    }
}

// ---- fused attention v5: S^T MFMA + packed LDS + FRAGMENT-ORDER bias --------
// c = mfma(kf, qf, bias): D[row=key][col=q]; bias acc-init is a single
// lane-contiguous 8B load (512B/instr coalesced). P[q][key] LDS: b64 writes,
// b128 A-frag reads. 6 LDS ops + 4 bias loads + 4 K/V loads per K-step.
__global__ __launch_bounds__(256) void attn_k(
    const __hip_bfloat16* __restrict__ Qw,
    const __hip_bfloat16* __restrict__ Kw,
    const __hip_bfloat16* __restrict__ Vtw,
    const __hip_bfloat16* __restrict__ biasF,
    __hip_bfloat16* __restrict__ AO) {
    __shared__ __attribute__((aligned(16))) __hip_bfloat16 Pt[4][32 * PTS];

    const int tid = threadIdx.x;
    const int wv = tid >> 6;
    const int pair = blockIdx.x * 4 + wv;    // 0..23 exactly
    const int bh = blockIdx.y;               // b*16 + h
    const int hh = bh & 15;
    const int b = bh >> 4;
    const int q0 = pair * 32;
    const int lane = tid & 63;
    const int lr = lane & 15, kc = lane >> 4;

    const __hip_bfloat16* Qb = Qw + (size_t)bh * NQ * HD;
    const __hip_bfloat16* Kb = Kw + (size_t)bh * NQ * HD;
    const __hip_bfloat16* Vb = Vtw + (size_t)bh * HD * VSTRIDE;
    __hip_bfloat16* Pw = &Pt[wv][0];

    int qrA = q0 + lr;      if (qrA > NQ - 1) qrA = NQ - 1;
    int qrB = q0 + 16 + lr; if (qrB > NQ - 1) qrB = NQ - 1;
    short8 qfA = *(const short8*)(const void*)(Qb + qrA * HD + kc * 8);
    short8 qfB = *(const short8*)(const void*)(Qb + qrB * HD + kc * 8);

    short8 onesf;
    {
        short s1 = (lr == 0) ? (short)0x3F80 : (short)0;
        #pragma unroll
        for (int j = 0; j < 8; ++j) onesf[j] = s1;
    }

    // fragment-order bias: [blk][kb 48][lane 64][4]; per K-step = 2 kb = 512 elems
    const __hip_bfloat16* bt0 = biasF + ((size_t)(hh * NQT + 2 * pair) * 48) * 256 + lane * 4;
    const __hip_bfloat16* bt1 = bt0 + 48 * 256;

    f32x4 oa0 = {}, ob0 = {}, ol0 = {};
    f32x4 oa1 = {}, ob1 = {}, ol1 = {};

    for (int ks = 0; ks < 24; ++ks) {
        const int k0 = ks * 32;
        int kr0 = k0 + lr;      if (kr0 > NQ - 1) kr0 = NQ - 1;
        int kr1 = k0 + 16 + lr; if (kr1 > NQ - 1) kr1 = NQ - 1;
        short8 kf0 = *(const short8*)(const void*)(Kb + kr0 * HD + kc * 8);
        short8 kf1 = *(const short8*)(const void*)(Kb + kr1 * HD + kc * 8);
        short8 vf0 = *(const short8*)(const void*)(Vb + (size_t)lr * VSTRIDE + k0 + kc * 8);
        short8 vf1 = *(const short8*)(const void*)(Vb + (size_t)(lr + 16) * VSTRIDE + k0 + kc * 8);

        // acc init: one coalesced 8B load per c-block
        f32x4 c0 = bias4(bt0 + ks * 512);
        f32x4 c1 = bias4(bt0 + ks * 512 + 256);
        f32x4 c2 = bias4(bt1 + ks * 512);
        f32x4 c3 = bias4(bt1 + ks * 512 + 256);

        // S^T: D[key][q]
        c0 = __builtin_amdgcn_mfma_f32_16x16x32_bf16(kf0, qfA, c0, 0, 0, 0);
        c1 = __builtin_amdgcn_mfma_f32_16x16x32_bf16(kf1, qfA, c1, 0, 0, 0);
        c2 = __builtin_amdgcn_mfma_f32_16x16x32_bf16(kf0, qfB, c2, 0, 0, 0);
        c3 = __builtin_amdgcn_mfma_f32_16x16x32_bf16(kf1, qfB, c3, 0, 0, 0);

        #pragma unroll
        for (int r = 0; r < 4; ++r) {
            c0[r] = fexp2(c0[r]); c1[r] = fexp2(c1[r]);
            c2[r] = fexp2(c2[r]); c3[r] = fexp2(c3[r]);
        }
        // P[q][key]: lane's 4 regs = 4 consecutive keys -> packed b64 writes
        pkstore(Pw + lr * PTS + kc * 4, c0);
        pkstore(Pw + lr * PTS + 16 + kc * 4, c1);
        pkstore(Pw + (16 + lr) * PTS + kc * 4, c2);
        pkstore(Pw + (16 + lr) * PTS + 16 + kc * 4, c3);
        asm volatile("" ::: "memory");
        __builtin_amdgcn_s_waitcnt(0xc07f);   // lgkmcnt(0); same-wave DS in order
        asm volatile("" ::: "memory");

        // A-frag: 8 consecutive keys at fixed q -> b128 reads
        short8 pfA = *(const short8*)(const void*)(Pw + lr * PTS + kc * 8);
        short8 pfB = *(const short8*)(const void*)(Pw + (16 + lr) * PTS + kc * 8);

        oa0 = __builtin_amdgcn_mfma_f32_16x16x32_bf16(pfA, vf0, oa0, 0, 0, 0);
        ob0 = __builtin_amdgcn_mfma_f32_16x16x32_bf16(pfA, vf1, ob0, 0, 0, 0);
        ol0 = __builtin_amdgcn_mfma_f32_16x16x32_bf16(pfA, onesf, ol0, 0, 0, 0);
        oa1 = __builtin_amdgcn_mfma_f32_16x16x32_bf16(pfB, vf0, oa1, 0, 0, 0);
        ob1 = __builtin_amdgcn_mfma_f32_16x16x32_bf16(pfB, vf1, ob1, 0, 0, 0);
        ol1 = __builtin_amdgcn_mfma_f32_16x16x32_bf16(pfB, onesf, ol1, 0, 0, 0);
    }

    #pragma unroll
    for (int r = 0; r < 4; ++r) {
        int row = kc * 4 + r;
        float lA = __shfl(ol0[r], lane & 48);
        float lB = __shfl(ol1[r], lane & 48);
        float liA = 1.0f / lA, liB = 1.0f / lB;
        int orA = q0 + row, orB = q0 + 16 + row;
        if (orA < NQ) {
            size_t base = ((size_t)b * NQ + orA) * CD + hh * HD;
            AO[base + lr]      = __hip_bfloat16(oa0[r] * liA);
            AO[base + 16 + lr] = __hip_bfloat16(ob0[r] * liA);
        }
        if (orB < NQ) {
            size_t base = ((size_t)b * NQ + orB) * CD + hh * HD;
            AO[base + lr]      = __hip_bfloat16(oa1[r] * liB);
            AO[base + 16 + lr] = __hip_bfloat16(ob1[r] * liB);
        }
    }
}

extern "C" void kernel_launch(void* const* d_in, const int* in_sizes, int n_in,
                              void* d_out, int out_size, void* d_ws, size_t ws_size,
                              hipStream_t stream) {
    char* ws = (char*)d_ws;
    size_t off = 0;
    auto carve = [&](size_t bytes) {
        char* p = ws + off;
        off += (bytes + 255) & ~(size_t)255;
        return p;
    };
    int* flagp = (int*)carve(256);
    __hip_bfloat16* Qw    = (__hip_bfloat16*)carve((size_t)256 * NQ * HD * 2);
    __hip_bfloat16* Kw    = (__hip_bfloat16*)carve((size_t)256 * NQ * HD * 2);
    __hip_bfloat16* Vtw   = (__hip_bfloat16*)carve((size_t)256 * HD * VSTRIDE * 2);
    __hip_bfloat16* WqT   = (__hip_bfloat16*)carve((size_t)1536 * 512 * 2);
    __hip_bfloat16* WpT   = (__hip_bfloat16*)carve((size_t)512 * 512 * 2);
    __hip_bfloat16* biasF = (__hip_bfloat16*)carve((size_t)16 * NQT * 48 * 64 * 4 * 2);
    __hip_bfloat16* Xb    = (__hip_bfloat16*)carve((size_t)MROWS * CD * 2);
    __hip_bfloat16* AO    = Xb;   // attn output overwrites x-staging (dead after qkv gemm)
    (void)ws_size; (void)in_sizes; (void)n_in; (void)out_size;

    sniff_k<<<dim3(1), dim3(64), 0, stream>>>((const unsigned int*)d_in[1], flagp);
    convx_k<<<dim3(5920), dim3(256), 0, stream>>>(d_in[0], (ushort4*)Xb, MROWS * CD / 4, flagp);
    transpose_k<<<dim3(48, 16), dim3(32, 8), 0, stream>>>(d_in[1], WqT, 512, 1536, flagp);
    transpose_k<<<dim3(16, 16), dim3(32, 8), 0, stream>>>(d_in[3], WpT, 512, 512, flagp);
    biasF_k<<<dim3(16 * NQT), dim3(256), 0, stream>>>(d_in[5], d_in[6], d_in[7], d_in[8],
                                                      d_in[9], d_in[10], biasF, flagp);
    gemm_qkv<<<dim3(47, 12), dim3(256), 0, stream>>>(Xb, WqT, d_in[2],
        Qw, Kw, Vtw, flagp);
    attn_k<<<dim3(6, 256), dim3(256), 0, stream>>>(Qw, Kw, Vtw, biasF, AO);
    gemm_bt<<<dim3(93, 4), dim3(256), 0, stream>>>(AO, WpT, d_in[4], MROWS,
        (__hip_bfloat16*)d_out, (float*)d_out, flagp);
}

// Round 9
// 284.557 us; speedup vs baseline: 1.1687x; 1.0019x over previous
//
#include <hip/hip_runtime.h>
#include <hip/hip_bf16.h>
#include <stdint.h>
#include <stddef.h>

typedef __attribute__((ext_vector_type(8))) short short8;
typedef __attribute__((ext_vector_type(4))) float f32x4;
typedef unsigned short ushort_t;

#define NHEADS 16
#define HD 32
#define NQ 740
#define NB 16
#define MROWS (NB*NQ)       // 11840
#define CD 512
#define KDIM 512
#define VSTRIDE 768         // v^T row stride
#define NQT 48              // padded q-tile slots for bias
#define PTS 40              // P[q][key] stride in bf16 (32 keys + 8 pad)
#define QS2 0.2550400865f   // hd^-0.5 * log2(e)
#define LOG2E 1.4426950409f
#define NEG_BIG -43000.0f   // log2e-scaled mask; v_exp_f32 flushes to 0

static __device__ __forceinline__ void gld_lds16(const void* g, void* l) {
    __builtin_amdgcn_global_load_lds((const __attribute__((address_space(1))) void*)g,
                                     (__attribute__((address_space(3))) void*)l,
                                     16, 0, 0);
}

static __device__ __forceinline__ float ldf(const void* p, int i, int fl) {
    return fl ? ((const float*)p)[i] : (float)((const __hip_bfloat16*)p)[i];
}
static __device__ __forceinline__ ushort_t f2bf(float f) {
    __hip_bfloat16 h(f);
    return *reinterpret_cast<ushort_t*>(&h);
}
static __device__ __forceinline__ float fexp2(float x) {
#if __has_builtin(__builtin_amdgcn_exp2f)
    return __builtin_amdgcn_exp2f(x);
#else
    return exp2f(x);
#endif
}
// unpack 4 packed bf16 (already in regs) -> f32x4
static __device__ __forceinline__ f32x4 bias4u(uint2 u) {
    f32x4 c;
    c[0] = __uint_as_float(u.x << 16);
    c[1] = __uint_as_float(u.x & 0xFFFF0000u);
    c[2] = __uint_as_float(u.y << 16);
    c[3] = __uint_as_float(u.y & 0xFFFF0000u);
    return c;
}
// pack f32x4 -> 4 bf16 (RNE, packed HW cvt), single 8B LDS store
static __device__ __forceinline__ void pkstore(__hip_bfloat16* dst, f32x4 c) {
    __hip_bfloat162* d = (__hip_bfloat162*)dst;
    d[0] = __float22bfloat162_rn(make_float2(c[0], c[1]));
    d[1] = __float22bfloat162_rn(make_float2(c[2], c[3]));
}
static __device__ __forceinline__ uint2 pk4(float a, float b, float c, float d) {
    __hip_bfloat162 p01 = __float22bfloat162_rn(make_float2(a, b));
    __hip_bfloat162 p23 = __float22bfloat162_rn(make_float2(c, d));
    uint2 u;
    u.x = *reinterpret_cast<unsigned int*>(&p01);
    u.y = *reinterpret_cast<unsigned int*>(&p23);
    return u;
}

// ------------- dtype sniff: fp32 arrays have uniform low-16 mantissa bits ----
__global__ __launch_bounds__(64) void sniff_k(const unsigned int* __restrict__ w,
                                              int* __restrict__ flag) {
    int cnt = 0;
    for (int i = threadIdx.x; i < 1024; i += 64) {
        unsigned int e = (w[i] >> 7) & 0xFFu;
        cnt += (e > 135u) ? 1 : 0;
    }
    #pragma unroll
    for (int d = 1; d < 64; d <<= 1) cnt += __shfl_xor(cnt, d);
    if (threadIdx.x == 0) *flag = (cnt > 16) ? 1 : 0;
}

// ------------- x normalization: fp32->bf16 (vectorized) or bf16 copy ---------
__global__ __launch_bounds__(256) void convx_k(const void* __restrict__ src,
                                               ushort4* __restrict__ dst,
                                               int nquads, const int* __restrict__ flag) {
    int i = blockIdx.x * 256 + threadIdx.x;
    if (i >= nquads) return;
    if (*flag) {
        float4 v = ((const float4*)src)[i];
        ushort4 o;
        o.x = f2bf(v.x); o.y = f2bf(v.y); o.z = f2bf(v.z); o.w = f2bf(v.w);
        dst[i] = o;
    } else {
        dst[i] = ((const ushort4*)src)[i];
    }
}

// ---------------- transpose + convert (for B^T weight layouts) ----------------
__global__ __launch_bounds__(256) void transpose_k(const void* __restrict__ src,
                                                   __hip_bfloat16* __restrict__ dst,
                                                   int R, int C, const int* __restrict__ flag) {
    __shared__ __hip_bfloat16 tile[32][33];
    const int fl = *flag;
    int bx = blockIdx.x * 32;   // col base in src
    int by = blockIdx.y * 32;   // row base in src
    int tx = threadIdx.x;
    for (int r = threadIdx.y; r < 32; r += 8)
        tile[r][tx] = __hip_bfloat16(ldf(src, (by + r) * C + bx + tx, fl));
    __syncthreads();
    for (int r = threadIdx.y; r < 32; r += 8)
        dst[(size_t)(bx + r) * R + by + tx] = tile[tx][r];
}

// -- bias * log2e in S^T MFMA FRAGMENT order: [blk=hh*48+qt][kb 48][lane 64][4]
__global__ __launch_bounds__(256) void biasF_k(
    const void* __restrict__ btT,    // bias_table_target [1849][16]
    const void* __restrict__ btt,    // bias_table_temp   [961][16]
    const void* __restrict__ ttab,   // temp_target_table [16][484]
    const void* __restrict__ tgtab,  // target_temp_table [16][256]
    const void* __restrict__ ttln,   // temp_target_line  [16][256]
    const void* __restrict__ tgln,   // target_temp_line  [16][484]
    __hip_bfloat16* __restrict__ biasF, const int* __restrict__ flag) {
    const int fl = *flag;
    const int blk = blockIdx.x;          // hh*48 + qt
    const int hh = blk / NQT;
    const int qt = blk - hh * NQT;
    for (int idx = threadIdx.x; idx < 48 * 64; idx += 256) {
        const int kb = idx >> 6;         // 16-key half-block
        const int lane = idx & 63;
        const int lr = lane & 15, kc = lane >> 4;
        int i = qt * 16 + lr; if (i > NQ - 1) i = NQ - 1;
        ushort4 o;
        ushort_t* op = (ushort_t*)&o;
        #pragma unroll
        for (int r = 0; r < 4; ++r) {
            int c = kb * 16 + kc * 4 + r;
            float v;
            if (c >= NQ) {
                v = NEG_BIG;
            } else if (i < 256) {
                if (c < 256) {
                    int t = ((i >> 4) - (c >> 4) + 15) * 31 + ((i & 15) - (c & 15) + 15);
                    v = ldf(btt, t * 16 + hh, fl) * LOG2E;
                } else {
                    v = (ldf(tgtab, hh * 256 + i, fl) + ldf(tgln, hh * 484 + (c - 256), fl)) * LOG2E;
                }
            } else {
                int ii = i - 256;
                if (c < 256) {
                    v = (ldf(ttab, hh * 484 + ii, fl) + ldf(ttln, hh * 256 + c, fl)) * LOG2E;
                } else {
                    int jj = c - 256;
                    int a = ii / 22, b2 = ii - a * 22;
                    int a2 = jj / 22, b3 = jj - a2 * 22;
                    int t = (a - a2 + 21) * 43 + (b2 - b3 + 21);
                    v = ldf(btT, t * 16 + hh, fl) * LOG2E;
                }
            }
            op[r] = f2bf(v);
        }
        ((ushort4*)biasF)[(size_t)blk * 48 * 64 + idx] = o;
    }
}

// ------- qkv GEMM: 256x128 tile; grid (n-blocks fastest) for A-tile L2 reuse -
__global__ __launch_bounds__(256) void gemm_qkv(
    const __hip_bfloat16* __restrict__ A,
    const __hip_bfloat16* __restrict__ Bt,
    const void* __restrict__ biasv,
    __hip_bfloat16* __restrict__ Qw,
    __hip_bfloat16* __restrict__ Kw,
    __hip_bfloat16* __restrict__ Vtw,
    const int* __restrict__ flag) {
    __shared__ __attribute__((aligned(16))) short sA[256 * 32];   // 16 KB
    __shared__ __attribute__((aligned(16))) short sB[128 * 32];   // 8 KB
    const int tid = threadIdx.x;
    const int lane = tid & 63;
    const int wv = tid >> 6;             // 0..3: 64-row group
    const int lr = lane & 15, kc = lane >> 4;
    const int m0 = blockIdx.y * 256;     // y = m-block (slow)
    const int n0 = blockIdx.x * 128;     // x = n-block (fast) -> A-tile reuse
    const int fl = *flag;
    const int M = MROWS;

    f32x4 acc[4][8] = {};

    for (int k0 = 0; k0 < KDIM; k0 += 32) {
        #pragma unroll
        for (int it = 0; it < 6; ++it) {
            int idx = it * 256 + tid;            // 16B unit index, 0..1535
            if (idx < 1024) {                    // A: 256 rows x 4 units
                int r = idx >> 2, c = idx & 3;
                int gr = m0 + r; if (gr > M - 1) gr = M - 1;
                gld_lds16(A + (size_t)gr * KDIM + k0 + c * 8, (char*)sA + idx * 16);
            } else {                             // B: 128 rows x 4 units
                int u = idx - 1024;
                int r = u >> 2, c = u & 3;
                gld_lds16(Bt + (size_t)(n0 + r) * KDIM + k0 + c * 8, (char*)sB + u * 16);
            }
        }
        __syncthreads();
        short8 af[4], bfr[8];
        #pragma unroll
        for (int t = 0; t < 4; ++t)
            af[t] = *(const short8*)&sA[(wv * 64 + t * 16 + lr) * 32 + kc * 8];
        #pragma unroll
        for (int t = 0; t < 8; ++t)
            bfr[t] = *(const short8*)&sB[(t * 16 + lr) * 32 + kc * 8];
        #pragma unroll
        for (int i = 0; i < 4; ++i)
            #pragma unroll
            for (int j = 0; j < 8; ++j)
                acc[i][j] = __builtin_amdgcn_mfma_f32_16x16x32_bf16(af[i], bfr[j], acc[i][j], 0, 0, 0);
        __syncthreads();
    }

    #pragma unroll
    for (int j = 0; j < 8; ++j) {
        int gn = n0 + j * 16 + lr;
        float bv = ldf(biasv, gn, fl);
        int s = gn >> 9;                  // 0:q 1:k 2:v
        int hh = (gn >> 5) & 15;
        int d = gn & 31;
        #pragma unroll
        for (int i = 0; i < 4; ++i) {
            int gm0 = m0 + wv * 64 + i * 16 + kc * 4;   // %4==0; group all-in or all-out
            if (gm0 >= M) continue;
            int b = gm0 / NQ;
            int nn = gm0 - b * NQ;                      // %4==0, no b-straddle in group
            size_t bh = (size_t)(b * 16 + hh);
            if (s == 2) {
                uint2 u = pk4(acc[i][j][0] + bv, acc[i][j][1] + bv,
                              acc[i][j][2] + bv, acc[i][j][3] + bv);
                *(uint2*)(void*)(Vtw + (bh * HD + d) * VSTRIDE + nn) = u;
            } else if (s == 0) {
                #pragma unroll
                for (int r = 0; r < 4; ++r)
                    Qw[(bh * NQ + nn + r) * HD + d] = __hip_bfloat16((acc[i][j][r] + bv) * QS2);
            } else {
                #pragma unroll
                for (int r = 0; r < 4; ++r)
                    Kw[(bh * NQ + nn + r) * HD + d] = __hip_bfloat16(acc[i][j][r] + bv);
            }
        }
    }
}

// ----- m97-style 128x128 bf16 GEMM (proj), grid n-fastest: Out = A@Bt^T+bias -
__global__ __launch_bounds__(256) void gemm_bt(
    const __hip_bfloat16* __restrict__ A,
    const __hip_bfloat16* __restrict__ Bt,
    const void* __restrict__ biasv,
    int M,
    __hip_bfloat16* __restrict__ Out,
    float* __restrict__ OutF,
    const int* __restrict__ flag) {
    __shared__ __attribute__((aligned(16))) short sA[128 * 32];
    __shared__ __attribute__((aligned(16))) short sB[128 * 32];
    const int tid = threadIdx.x;
    const int lane = tid & 63;
    const int wv = tid >> 6;
    const int wr = wv >> 1, wc = wv & 1;
    const int lr = lane & 15, kc = lane >> 4;
    const int m0 = blockIdx.y * 128;     // y = m (slow)
    const int n0 = blockIdx.x * 128;     // x = n (fast) -> A-tile reuse
    const int fl = *flag;

    f32x4 acc[4][4] = {};

    for (int k0 = 0; k0 < KDIM; k0 += 32) {
        #pragma unroll
        for (int it = 0; it < 2; ++it) {
            int idx = it * 256 + tid;           // 16-byte unit index
            int r = idx >> 2;
            int c = idx & 3;
            int gr = m0 + r; if (gr > M - 1) gr = M - 1;
            gld_lds16(A + (size_t)gr * KDIM + k0 + c * 8, (char*)sA + idx * 16);
            gld_lds16(Bt + (size_t)(n0 + r) * KDIM + k0 + c * 8, (char*)sB + idx * 16);
        }
        __syncthreads();
        short8 af[4], bfr[4];
        #pragma unroll
        for (int t = 0; t < 4; ++t)
            af[t] = *(const short8*)&sA[(wr * 64 + t * 16 + lr) * 32 + kc * 8];
        #pragma unroll
        for (int t = 0; t < 4; ++t)
            bfr[t] = *(const short8*)&sB[(wc * 64 + t * 16 + lr) * 32 + kc * 8];
        #pragma unroll
        for (int i = 0; i < 4; ++i)
            #pragma unroll
            for (int j = 0; j < 4; ++j)
                acc[i][j] = __builtin_amdgcn_mfma_f32_16x16x32_bf16(af[i], bfr[j], acc[i][j], 0, 0, 0);
        __syncthreads();
    }

    #pragma unroll
    for (int i = 0; i < 4; ++i) {
        #pragma unroll
        for (int j = 0; j < 4; ++j) {
            int gn = n0 + wc * 64 + j * 16 + lr;
            float bv = ldf(biasv, gn, fl);
            #pragma unroll
            for (int r = 0; r < 4; ++r) {
                int gm = m0 + wr * 64 + i * 16 + kc * 4 + r;
                if (gm < M) {
                    float v = acc[i][j][r] + bv;
                    if (fl) OutF[(size_t)gm * CD + gn] = v;
                    else    Out[(size_t)gm * CD + gn] = __hip_bfloat16(v);
                }
            }
        }
    }
}

// ---- fused attention v6: S^T MFMA + packed LDS + reg-ping-pong prefetch -----
// Next step's K-frags + bias issued BEFORE the LDS fence so their latency
// overlaps the exp2/LDS/PV section. No row clamps: overruns land in adjacent
// ws buffers (finite) and are masked by NEG_BIG bias / epilogue guards.
__global__ __launch_bounds__(256) void attn_k(
    const __hip_bfloat16* __restrict__ Qw,
    const __hip_bfloat16* __restrict__ Kw,
    const __hip_bfloat16* __restrict__ Vtw,
    const __hip_bfloat16* __restrict__ biasF,
    __hip_bfloat16* __restrict__ AO) {
    __shared__ __attribute__((aligned(16))) __hip_bfloat16 Pt[4][32 * PTS];

    const int tid = threadIdx.x;
    const int wv = tid >> 6;
    const int pair = blockIdx.x * 4 + wv;    // 0..23 exactly
    const int bh = blockIdx.y;               // b*16 + h
    const int hh = bh & 15;
    const int b = bh >> 4;
    const int q0 = pair * 32;
    const int lane = tid & 63;
    const int lr = lane & 15, kc = lane >> 4;

    const __hip_bfloat16* Qb = Qw + (size_t)bh * NQ * HD;
    const __hip_bfloat16* Kb = Kw + (size_t)bh * NQ * HD;
    const __hip_bfloat16* Vb = Vtw + (size_t)bh * HD * VSTRIDE;
    __hip_bfloat16* Pw = &Pt[wv][0];

    short8 qfA = *(const short8*)(const void*)(Qb + (q0 + lr) * HD + kc * 8);
    short8 qfB = *(const short8*)(const void*)(Qb + (q0 + 16 + lr) * HD + kc * 8);

    short8 onesf;
    {
        short s1 = (lr == 0) ? (short)0x3F80 : (short)0;
        #pragma unroll
        for (int j = 0; j < 8; ++j) onesf[j] = s1;
    }

    // fragment-order bias: [blk][kb 48][lane 64][4]; per K-step = 512 elems
    const __hip_bfloat16* bt0 = biasF + ((size_t)(hh * NQT + 2 * pair) * 48) * 256 + lane * 4;
    const __hip_bfloat16* bt1 = bt0 + 48 * 256;

    // ping-pong prefetch registers (K + bias)
    short8 kfa[2], kfb[2];
    uint2 br0[2], br1[2], br2[2], br3[2];
    kfa[0] = *(const short8*)(const void*)(Kb + lr * HD + kc * 8);
    kfb[0] = *(const short8*)(const void*)(Kb + (16 + lr) * HD + kc * 8);
    br0[0] = *(const uint2*)(const void*)(bt0);
    br1[0] = *(const uint2*)(const void*)(bt0 + 256);
    br2[0] = *(const uint2*)(const void*)(bt1);
    br3[0] = *(const uint2*)(const void*)(bt1 + 256);

    f32x4 oa0 = {}, ob0 = {}, ol0 = {};
    f32x4 oa1 = {}, ob1 = {}, ol1 = {};

    #pragma unroll
    for (int ks = 0; ks < 24; ++ks) {
        const int cur = ks & 1, nxt = cur ^ 1;
        const int k0 = ks * 32;

        f32x4 c0 = bias4u(br0[cur]);
        f32x4 c1 = bias4u(br1[cur]);
        f32x4 c2 = bias4u(br2[cur]);
        f32x4 c3 = bias4u(br3[cur]);

        // S^T: D[key][q]
        c0 = __builtin_amdgcn_mfma_f32_16x16x32_bf16(kfa[cur], qfA, c0, 0, 0, 0);
        c1 = __builtin_amdgcn_mfma_f32_16x16x32_bf16(kfb[cur], qfA, c1, 0, 0, 0);
        c2 = __builtin_amdgcn_mfma_f32_16x16x32_bf16(kfa[cur], qfB, c2, 0, 0, 0);
        c3 = __builtin_amdgcn_mfma_f32_16x16x32_bf16(kfb[cur], qfB, c3, 0, 0, 0);

        // prefetch next step's K + bias (latency hidden behind exp2/LDS/PV)
        if (ks < 23) {
            const int k0n = k0 + 32;
            kfa[nxt] = *(const short8*)(const void*)(Kb + (k0n + lr) * HD + kc * 8);
            kfb[nxt] = *(const short8*)(const void*)(Kb + (k0n + 16 + lr) * HD + kc * 8);
            br0[nxt] = *(const uint2*)(const void*)(bt0 + (ks + 1) * 512);
            br1[nxt] = *(const uint2*)(const void*)(bt0 + (ks + 1) * 512 + 256);
            br2[nxt] = *(const uint2*)(const void*)(bt1 + (ks + 1) * 512);
            br3[nxt] = *(const uint2*)(const void*)(bt1 + (ks + 1) * 512 + 256);
        }
        // V for the current step: ~exp2+LDS latency ahead of its PV use
        short8 vf0 = *(const short8*)(const void*)(Vb + lr * VSTRIDE + k0 + kc * 8);
        short8 vf1 = *(const short8*)(const void*)(Vb + (lr + 16) * VSTRIDE + k0 + kc * 8);

        #pragma unroll
        for (int r = 0; r < 4; ++r) {
            c0[r] = fexp2(c0[r]); c1[r] = fexp2(c1[r]);
            c2[r] = fexp2(c2[r]); c3[r] = fexp2(c3[r]);
        }
        // P[q][key]: lane's 4 regs = 4 consecutive keys -> packed b64 writes
        pkstore(Pw + lr * PTS + kc * 4, c0);
        pkstore(Pw + lr * PTS + 16 + kc * 4, c1);
        pkstore(Pw + (16 + lr) * PTS + kc * 4, c2);
        pkstore(Pw + (16 + lr) * PTS + 16 + kc * 4, c3);
        asm volatile("" ::: "memory");
        __builtin_amdgcn_s_waitcnt(0xc07f);   // lgkmcnt(0); same-wave DS in order
        asm volatile("" ::: "memory");

        // A-frag: 8 consecutive keys at fixed q -> b128 reads
        short8 pfA = *(const short8*)(const void*)(Pw + lr * PTS + kc * 8);
        short8 pfB = *(const short8*)(const void*)(Pw + (16 + lr) * PTS + kc * 8);

        oa0 = __builtin_amdgcn_mfma_f32_16x16x32_bf16(pfA, vf0, oa0, 0, 0, 0);
        ob0 = __builtin_amdgcn_mfma_f32_16x16x32_bf16(pfA, vf1, ob0, 0, 0, 0);
        ol0 = __builtin_amdgcn_mfma_f32_16x16x32_bf16(pfA, onesf, ol0, 0, 0, 0);
        oa1 = __builtin_amdgcn_mfma_f32_16x16x32_bf16(pfB, vf0, oa1, 0, 0, 0);
        ob1 = __builtin_amdgcn_mfma_f32_16x16x32_bf16(pfB, vf1, ob1, 0, 0, 0);
        ol1 = __builtin_amdgcn_mfma_f32_16x16x32_bf16(pfB, onesf, ol1, 0, 0, 0);
    }

    #pragma unroll
    for (int r = 0; r < 4; ++r) {
        int row = kc * 4 + r;
        float lA = __shfl(ol0[r], lane & 48);
        float lB = __shfl(ol1[r], lane & 48);
        float liA = 1.0f / lA, liB = 1.0f / lB;
        int orA = q0 + row, orB = q0 + 16 + row;
        if (orA < NQ) {
            size_t base = ((size_t)b * NQ + orA) * CD + hh * HD;
            AO[base + lr]      = __hip_bfloat16(oa0[r] * liA);
            AO[base + 16 + lr] = __hip_bfloat16(ob0[r] * liA);
        }
        if (orB < NQ) {
            size_t base = ((size_t)b * NQ + orB) * CD + hh * HD;
            AO[base + lr]      = __hip_bfloat16(oa1[r] * liB);
            AO[base + 16 + lr] = __hip_bfloat16(ob1[r] * liB);
        }
    }
}

extern "C" void kernel_launch(void* const* d_in, const int* in_sizes, int n_in,
                              void* d_out, int out_size, void* d_ws, size_t ws_size,
                              hipStream_t stream) {
    char* ws = (char*)d_ws;
    size_t off = 0;
    auto carve = [&](size_t bytes) {
        char* p = ws + off;
        off += (bytes + 255) & ~(size_t)255;
        return p;
    };
    int* flagp = (int*)carve(256);
    __hip_bfloat16* Qw    = (__hip_bfloat16*)carve((size_t)256 * NQ * HD * 2);
    __hip_bfloat16* Kw    = (__hip_bfloat16*)carve((size_t)256 * NQ * HD * 2);
    __hip_bfloat16* Vtw   = (__hip_bfloat16*)carve((size_t)256 * HD * VSTRIDE * 2);
    __hip_bfloat16* WqT   = (__hip_bfloat16*)carve((size_t)1536 * 512 * 2);
    __hip_bfloat16* WpT   = (__hip_bfloat16*)carve((size_t)512 * 512 * 2);
    __hip_bfloat16* biasF = (__hip_bfloat16*)carve((size_t)16 * NQT * 48 * 64 * 4 * 2);
    __hip_bfloat16* Xb    = (__hip_bfloat16*)carve((size_t)MROWS * CD * 2);
    __hip_bfloat16* AO    = Xb;   // attn output overwrites x-staging (dead after qkv gemm)
    (void)ws_size; (void)in_sizes; (void)n_in; (void)out_size;

    sniff_k<<<dim3(1), dim3(64), 0, stream>>>((const unsigned int*)d_in[1], flagp);
    convx_k<<<dim3(5920), dim3(256), 0, stream>>>(d_in[0], (ushort4*)Xb, MROWS * CD / 4, flagp);
    transpose_k<<<dim3(48, 16), dim3(32, 8), 0, stream>>>(d_in[1], WqT, 512, 1536, flagp);
    transpose_k<<<dim3(16, 16), dim3(32, 8), 0, stream>>>(d_in[3], WpT, 512, 512, flagp);
    biasF_k<<<dim3(16 * NQT), dim3(256), 0, stream>>>(d_in[5], d_in[6], d_in[7], d_in[8],
                                                      d_in[9], d_in[10], biasF, flagp);
    gemm_qkv<<<dim3(12, 47), dim3(256), 0, stream>>>(Xb, WqT, d_in[2],
        Qw, Kw, Vtw, flagp);
    attn_k<<<dim3(6, 256), dim3(256), 0, stream>>>(Qw, Kw, Vtw, biasF, AO);
    gemm_bt<<<dim3(4, 93), dim3(256), 0, stream>>>(AO, WpT, d_in[4], MROWS,
        (__hip_bfloat16*)d_out, (float*)d_out, flagp);
}

// Round 10
// 274.405 us; speedup vs baseline: 1.2119x; 1.0370x over previous
//
#include <hip/hip_runtime.h>
#include <hip/hip_bf16.h>
#include <stdint.h>
#include <stddef.h>

typedef __attribute__((ext_vector_type(8))) short short8;
typedef __attribute__((ext_vector_type(4))) float f32x4;
typedef unsigned short ushort_t;

#define NHEADS 16
#define HD 32
#define NQ 740
#define NB 16
#define MROWS (NB*NQ)       // 11840
#define CD 512
#define KDIM 512
#define VSTRIDE 768         // v^T row stride
#define NQT 48              // padded q-tile slots for bias
#define PTS 40              // P[q][key] stride in bf16 (32 keys + 8 pad)
#define QS2 0.2550400865f   // hd^-0.5 * log2(e)
#define LOG2E 1.4426950409f
#define NEG_BIG -43000.0f   // log2e-scaled mask; v_exp_f32 flushes to 0

static __device__ __forceinline__ void gld_lds16(const void* g, void* l) {
    __builtin_amdgcn_global_load_lds((const __attribute__((address_space(1))) void*)g,
                                     (__attribute__((address_space(3))) void*)l,
                                     16, 0, 0);
}

static __device__ __forceinline__ float ldf(const void* p, int i, int fl) {
    return fl ? ((const float*)p)[i] : (float)((const __hip_bfloat16*)p)[i];
}
static __device__ __forceinline__ ushort_t f2bf(float f) {
    __hip_bfloat16 h(f);
    return *reinterpret_cast<ushort_t*>(&h);
}
static __device__ __forceinline__ float fexp2(float x) {
#if __has_builtin(__builtin_amdgcn_exp2f)
    return __builtin_amdgcn_exp2f(x);
#else
    return exp2f(x);
#endif
}
// unpack 4 packed bf16 (already in regs) -> f32x4
static __device__ __forceinline__ f32x4 bias4u(uint2 u) {
    f32x4 c;
    c[0] = __uint_as_float(u.x << 16);
    c[1] = __uint_as_float(u.x & 0xFFFF0000u);
    c[2] = __uint_as_float(u.y << 16);
    c[3] = __uint_as_float(u.y & 0xFFFF0000u);
    return c;
}
// pack f32x4 -> 4 bf16 (RNE, packed HW cvt), single 8B LDS store
static __device__ __forceinline__ void pkstore(__hip_bfloat16* dst, f32x4 c) {
    __hip_bfloat162* d = (__hip_bfloat162*)dst;
    d[0] = __float22bfloat162_rn(make_float2(c[0], c[1]));
    d[1] = __float22bfloat162_rn(make_float2(c[2], c[3]));
}
static __device__ __forceinline__ uint2 pk4(float a, float b, float c, float d) {
    __hip_bfloat162 p01 = __float22bfloat162_rn(make_float2(a, b));
    __hip_bfloat162 p23 = __float22bfloat162_rn(make_float2(c, d));
    uint2 u;
    u.x = *reinterpret_cast<unsigned int*>(&p01);
    u.y = *reinterpret_cast<unsigned int*>(&p23);
    return u;
}

// ------------- dtype sniff: fp32 arrays have uniform low-16 mantissa bits ----
__global__ __launch_bounds__(64) void sniff_k(const unsigned int* __restrict__ w,
                                              int* __restrict__ flag) {
    int cnt = 0;
    for (int i = threadIdx.x; i < 1024; i += 64) {
        unsigned int e = (w[i] >> 7) & 0xFFu;
        cnt += (e > 135u) ? 1 : 0;
    }
    #pragma unroll
    for (int d = 1; d < 64; d <<= 1) cnt += __shfl_xor(cnt, d);
    if (threadIdx.x == 0) *flag = (cnt > 16) ? 1 : 0;
}

// ------------- x normalization: fp32->bf16 (vectorized) or bf16 copy ---------
__global__ __launch_bounds__(256) void convx_k(const void* __restrict__ src,
                                               ushort4* __restrict__ dst,
                                               int nquads, const int* __restrict__ flag) {
    int i = blockIdx.x * 256 + threadIdx.x;
    if (i >= nquads) return;
    if (*flag) {
        float4 v = ((const float4*)src)[i];
        ushort4 o;
        o.x = f2bf(v.x); o.y = f2bf(v.y); o.z = f2bf(v.z); o.w = f2bf(v.w);
        dst[i] = o;
    } else {
        dst[i] = ((const ushort4*)src)[i];
    }
}

// ---------------- transpose + convert (for B^T weight layouts) ----------------
__global__ __launch_bounds__(256) void transpose_k(const void* __restrict__ src,
                                                   __hip_bfloat16* __restrict__ dst,
                                                   int R, int C, const int* __restrict__ flag) {
    __shared__ __hip_bfloat16 tile[32][33];
    const int fl = *flag;
    int bx = blockIdx.x * 32;   // col base in src
    int by = blockIdx.y * 32;   // row base in src
    int tx = threadIdx.x;
    for (int r = threadIdx.y; r < 32; r += 8)
        tile[r][tx] = __hip_bfloat16(ldf(src, (by + r) * C + bx + tx, fl));
    __syncthreads();
    for (int r = threadIdx.y; r < 32; r += 8)
        dst[(size_t)(bx + r) * R + by + tx] = tile[tx][r];
}

// -- bias * log2e in S^T MFMA FRAGMENT order: [blk=hh*48+qt][kb 48][lane 64][4]
__global__ __launch_bounds__(256) void biasF_k(
    const void* __restrict__ btT,    // bias_table_target [1849][16]
    const void* __restrict__ btt,    // bias_table_temp   [961][16]
    const void* __restrict__ ttab,   // temp_target_table [16][484]
    const void* __restrict__ tgtab,  // target_temp_table [16][256]
    const void* __restrict__ ttln,   // temp_target_line  [16][256]
    const void* __restrict__ tgln,   // target_temp_line  [16][484]
    __hip_bfloat16* __restrict__ biasF, const int* __restrict__ flag) {
    const int fl = *flag;
    const int blk = blockIdx.x;          // hh*48 + qt
    const int hh = blk / NQT;
    const int qt = blk - hh * NQT;
    for (int idx = threadIdx.x; idx < 48 * 64; idx += 256) {
        const int kb = idx >> 6;         // 16-key half-block
        const int lane = idx & 63;
        const int lr = lane & 15, kc = lane >> 4;
        int i = qt * 16 + lr; if (i > NQ - 1) i = NQ - 1;
        ushort4 o;
        ushort_t* op = (ushort_t*)&o;
        #pragma unroll
        for (int r = 0; r < 4; ++r) {
            int c = kb * 16 + kc * 4 + r;
            float v;
            if (c >= NQ) {
                v = NEG_BIG;
            } else if (i < 256) {
                if (c < 256) {
                    int t = ((i >> 4) - (c >> 4) + 15) * 31 + ((i & 15) - (c & 15) + 15);
                    v = ldf(btt, t * 16 + hh, fl) * LOG2E;
                } else {
                    v = (ldf(tgtab, hh * 256 + i, fl) + ldf(tgln, hh * 484 + (c - 256), fl)) * LOG2E;
                }
            } else {
                int ii = i - 256;
                if (c < 256) {
                    v = (ldf(ttab, hh * 484 + ii, fl) + ldf(ttln, hh * 256 + c, fl)) * LOG2E;
                } else {
                    int jj = c - 256;
                    int a = ii / 22, b2 = ii - a * 22;
                    int a2 = jj / 22, b3 = jj - a2 * 22;
                    int t = (a - a2 + 21) * 43 + (b2 - b3 + 21);
                    v = ldf(btT, t * 16 + hh, fl) * LOG2E;
                }
            }
            op[r] = f2bf(v);
        }
        ((ushort4*)biasF)[(size_t)blk * 48 * 64 + idx] = o;
    }
}

// ------- qkv GEMM: 256x128 tile, n-fastest grid; LDS-repacked epilogue -------
// K-loop unchanged (m97-style). Epilogue: per wave, each head's 64x32 output
// goes through a 5KB wave-private LDS tile, then out as fully-coalesced
// b128 stores (no more 2B scattered writes = no partial-line HBM penalty).
__global__ __launch_bounds__(256) void gemm_qkv(
    const __hip_bfloat16* __restrict__ A,
    const __hip_bfloat16* __restrict__ Bt,
    const void* __restrict__ biasv,
    __hip_bfloat16* __restrict__ Qw,
    __hip_bfloat16* __restrict__ Kw,
    __hip_bfloat16* __restrict__ Vtw,
    const int* __restrict__ flag) {
    __shared__ __attribute__((aligned(16))) short sMem[256 * 32 + 128 * 32];  // 24 KB
    short* sA = sMem;                // 256x32
    short* sB = sMem + 256 * 32;     // 128x32
    const int tid = threadIdx.x;
    const int lane = tid & 63;
    const int wv = tid >> 6;             // 0..3: 64-row group
    const int lr = lane & 15, kc = lane >> 4;
    const int m0 = blockIdx.y * 256;     // y = m-block (slow)
    const int n0 = blockIdx.x * 128;     // x = n-block (fast) -> A-tile reuse
    const int fl = *flag;
    const int M = MROWS;

    f32x4 acc[4][8] = {};

    for (int k0 = 0; k0 < KDIM; k0 += 32) {
        #pragma unroll
        for (int it = 0; it < 6; ++it) {
            int idx = it * 256 + tid;            // 16B unit index, 0..1535
            if (idx < 1024) {                    // A: 256 rows x 4 units
                int r = idx >> 2, c = idx & 3;
                int gr = m0 + r; if (gr > M - 1) gr = M - 1;
                gld_lds16(A + (size_t)gr * KDIM + k0 + c * 8, (char*)sA + idx * 16);
            } else {                             // B: 128 rows x 4 units
                int u = idx - 1024;
                int r = u >> 2, c = u & 3;
                gld_lds16(Bt + (size_t)(n0 + r) * KDIM + k0 + c * 8, (char*)sB + u * 16);
            }
        }
        __syncthreads();
        short8 af[4], bfr[8];
        #pragma unroll
        for (int t = 0; t < 4; ++t)
            af[t] = *(const short8*)&sA[(wv * 64 + t * 16 + lr) * 32 + kc * 8];
        #pragma unroll
        for (int t = 0; t < 8; ++t)
            bfr[t] = *(const short8*)&sB[(t * 16 + lr) * 32 + kc * 8];
        #pragma unroll
        for (int i = 0; i < 4; ++i)
            #pragma unroll
            for (int j = 0; j < 8; ++j)
                acc[i][j] = __builtin_amdgcn_mfma_f32_16x16x32_bf16(af[i], bfr[j], acc[i][j], 0, 0, 0);
        __syncthreads();
    }

    // ---- epilogue: LDS repack -> coalesced global stores ----
    const int s = n0 >> 9;                      // 0:q 1:k 2:v, uniform per WG
    short* Tw = sMem + wv * 2560;               // per-wave 5KB scratch
    const int gmr = m0 + wv * 64 + lane;        // q/k: row this lane stores
    int gmrc = gmr < M ? gmr : M - 1;
    int bq = gmrc / NQ;
    int nnq = gmrc - bq * NQ;
    const int gmv = m0 + wv * 64 + (lane & 15) * 4;   // v: 4-row quad (740%4==0)
    int gmvc = gmv < M ? gmv : M - 1;
    int bv2 = gmvc / NQ;
    int nnv = gmvc - bv2 * NQ;

    #pragma unroll
    for (int t = 0; t < 4; ++t) {
        const int hh = ((n0 >> 5) + t) & 15;
        float bva = ldf(biasv, n0 + t * 32 + lr, fl);
        float bvb = ldf(biasv, n0 + t * 32 + 16 + lr, fl);
        asm volatile("" ::: "memory");
        if (s == 2) {
            // Tv[32 d][72]: d rows, nn contiguous; b64 packed writes
            #pragma unroll
            for (int i = 0; i < 4; ++i) {
                int nl = i * 16 + kc * 4;
                uint2 ua = pk4(acc[i][2*t][0] + bva, acc[i][2*t][1] + bva,
                               acc[i][2*t][2] + bva, acc[i][2*t][3] + bva);
                uint2 ub = pk4(acc[i][2*t+1][0] + bvb, acc[i][2*t+1][1] + bvb,
                               acc[i][2*t+1][2] + bvb, acc[i][2*t+1][3] + bvb);
                *(uint2*)(void*)&Tw[lr * 72 + nl]        = ua;
                *(uint2*)(void*)&Tw[(16 + lr) * 72 + nl] = ub;
            }
        } else {
            // Tq[64 nn][40]: nn rows, d contiguous; scalar writes (LDS-cheap)
            float sc = (s == 0) ? QS2 : 1.0f;
            #pragma unroll
            for (int i = 0; i < 4; ++i)
                #pragma unroll
                for (int r = 0; r < 4; ++r) {
                    int nl = i * 16 + kc * 4 + r;
                    Tw[nl * 40 + lr]      = (short)f2bf((acc[i][2*t][r]   + bva) * sc);
                    Tw[nl * 40 + 16 + lr] = (short)f2bf((acc[i][2*t+1][r] + bvb) * sc);
                }
        }
        asm volatile("" ::: "memory");
        __builtin_amdgcn_s_waitcnt(0xc07f);   // lgkmcnt(0); same-wave DS in order
        asm volatile("" ::: "memory");
        if (s == 2) {
            if (gmv < M) {
                size_t bh = (size_t)(bv2 * 16 + hh);
                #pragma unroll
                for (int i2 = 0; i2 < 8; ++i2) {
                    int d = (lane >> 4) + i2 * 4;
                    uint2 u = *(const uint2*)(const void*)&Tw[d * 72 + (lane & 15) * 4];
                    *(uint2*)(void*)(Vtw + (bh * HD + d) * VSTRIDE + nnv) = u;
                }
            }
        } else {
            if (gmr < M) {
                size_t bh = (size_t)(bq * 16 + hh);
                __hip_bfloat16* dst = (s == 0 ? Qw : Kw) + (bh * NQ + nnq) * HD;
                #pragma unroll
                for (int c = 0; c < 4; ++c) {
                    short8 u = *(const short8*)(const void*)&Tw[lane * 40 + c * 8];
                    *(short8*)(void*)(dst + c * 8) = u;
                }
            }
        }
        asm volatile("" ::: "memory");
        __builtin_amdgcn_s_waitcnt(0xc07f);   // reads drained before next-t writes
        asm volatile("" ::: "memory");
    }
}

// ----- m97-style 128x128 bf16 GEMM (proj), grid n-fastest: Out = A@Bt^T+bias -
__global__ __launch_bounds__(256) void gemm_bt(
    const __hip_bfloat16* __restrict__ A,
    const __hip_bfloat16* __restrict__ Bt,
    const void* __restrict__ biasv,
    int M,
    __hip_bfloat16* __restrict__ Out,
    float* __restrict__ OutF,
    const int* __restrict__ flag) {
    __shared__ __attribute__((aligned(16))) short sA[128 * 32];
    __shared__ __attribute__((aligned(16))) short sB[128 * 32];
    const int tid = threadIdx.x;
    const int lane = tid & 63;
    const int wv = tid >> 6;
    const int wr = wv >> 1, wc = wv & 1;
    const int lr = lane & 15, kc = lane >> 4;
    const int m0 = blockIdx.y * 128;     // y = m (slow)
    const int n0 = blockIdx.x * 128;     // x = n (fast) -> A-tile reuse
    const int fl = *flag;

    f32x4 acc[4][4] = {};

    for (int k0 = 0; k0 < KDIM; k0 += 32) {
        #pragma unroll
        for (int it = 0; it < 2; ++it) {
            int idx = it * 256 + tid;           // 16-byte unit index
            int r = idx >> 2;
            int c = idx & 3;
            int gr = m0 + r; if (gr > M - 1) gr = M - 1;
            gld_lds16(A + (size_t)gr * KDIM + k0 + c * 8, (char*)sA + idx * 16);
            gld_lds16(Bt + (size_t)(n0 + r) * KDIM + k0 + c * 8, (char*)sB + idx * 16);
        }
        __syncthreads();
        short8 af[4], bfr[4];
        #pragma unroll
        for (int t = 0; t < 4; ++t)
            af[t] = *(const short8*)&sA[(wr * 64 + t * 16 + lr) * 32 + kc * 8];
        #pragma unroll
        for (int t = 0; t < 4; ++t)
            bfr[t] = *(const short8*)&sB[(wc * 64 + t * 16 + lr) * 32 + kc * 8];
        #pragma unroll
        for (int i = 0; i < 4; ++i)
            #pragma unroll
            for (int j = 0; j < 4; ++j)
                acc[i][j] = __builtin_amdgcn_mfma_f32_16x16x32_bf16(af[i], bfr[j], acc[i][j], 0, 0, 0);
        __syncthreads();
    }

    #pragma unroll
    for (int i = 0; i < 4; ++i) {
        #pragma unroll
        for (int j = 0; j < 4; ++j) {
            int gn = n0 + wc * 64 + j * 16 + lr;
            float bv = ldf(biasv, gn, fl);
            #pragma unroll
            for (int r = 0; r < 4; ++r) {
                int gm = m0 + wr * 64 + i * 16 + kc * 4 + r;
                if (gm < M) {
                    float v = acc[i][j][r] + bv;
                    if (fl) OutF[(size_t)gm * CD + gn] = v;
                    else    Out[(size_t)gm * CD + gn] = __hip_bfloat16(v);
                }
            }
        }
    }
}

// ---- fused attention v7: S^T MFMA + packed LDS + prefetch + h-major grid ----
// Grid y decode: hh = y>>4, b = y&15 -> 16 consecutive WGs share one bias
// slab (1.2MB, L2-resident) instead of thrashing 16 slabs.
__global__ __launch_bounds__(256) void attn_k(
    const __hip_bfloat16* __restrict__ Qw,
    const __hip_bfloat16* __restrict__ Kw,
    const __hip_bfloat16* __restrict__ Vtw,
    const __hip_bfloat16* __restrict__ biasF,
    __hip_bfloat16* __restrict__ AO) {
    __shared__ __attribute__((aligned(16))) __hip_bfloat16 Pt[4][32 * PTS];

    const int tid = threadIdx.x;
    const int wv = tid >> 6;
    const int pair = blockIdx.x * 4 + wv;    // 0..23 exactly
    const int yy = blockIdx.y;
    const int hh = yy >> 4;                  // slow -> bias slab shared
    const int b  = yy & 15;
    const size_t bhd = (size_t)(b * 16 + hh);
    const int q0 = pair * 32;
    const int lane = tid & 63;
    const int lr = lane & 15, kc = lane >> 4;

    const __hip_bfloat16* Qb = Qw + bhd * NQ * HD;
    const __hip_bfloat16* Kb = Kw + bhd * NQ * HD;
    const __hip_bfloat16* Vb = Vtw + bhd * HD * VSTRIDE;
    __hip_bfloat16* Pw = &Pt[wv][0];

    short8 qfA = *(const short8*)(const void*)(Qb + (q0 + lr) * HD + kc * 8);
    short8 qfB = *(const short8*)(const void*)(Qb + (q0 + 16 + lr) * HD + kc * 8);

    short8 onesf;
    {
        short s1 = (lr == 0) ? (short)0x3F80 : (short)0;
        #pragma unroll
        for (int j = 0; j < 8; ++j) onesf[j] = s1;
    }

    // fragment-order bias: [blk][kb 48][lane 64][4]; per K-step = 512 elems
    const __hip_bfloat16* bt0 = biasF + ((size_t)(hh * NQT + 2 * pair) * 48) * 256 + lane * 4;
    const __hip_bfloat16* bt1 = bt0 + 48 * 256;

    // ping-pong prefetch registers (K + bias)
    short8 kfa[2], kfb[2];
    uint2 br0[2], br1[2], br2[2], br3[2];
    kfa[0] = *(const short8*)(const void*)(Kb + lr * HD + kc * 8);
    kfb[0] = *(const short8*)(const void*)(Kb + (16 + lr) * HD + kc * 8);
    br0[0] = *(const uint2*)(const void*)(bt0);
    br1[0] = *(const uint2*)(const void*)(bt0 + 256);
    br2[0] = *(const uint2*)(const void*)(bt1);
    br3[0] = *(const uint2*)(const void*)(bt1 + 256);

    f32x4 oa0 = {}, ob0 = {}, ol0 = {};
    f32x4 oa1 = {}, ob1 = {}, ol1 = {};

    #pragma unroll
    for (int ks = 0; ks < 24; ++ks) {
        const int cur = ks & 1, nxt = cur ^ 1;
        const int k0 = ks * 32;

        f32x4 c0 = bias4u(br0[cur]);
        f32x4 c1 = bias4u(br1[cur]);
        f32x4 c2 = bias4u(br2[cur]);
        f32x4 c3 = bias4u(br3[cur]);

        // S^T: D[key][q]
        c0 = __builtin_amdgcn_mfma_f32_16x16x32_bf16(kfa[cur], qfA, c0, 0, 0, 0);
        c1 = __builtin_amdgcn_mfma_f32_16x16x32_bf16(kfb[cur], qfA, c1, 0, 0, 0);
        c2 = __builtin_amdgcn_mfma_f32_16x16x32_bf16(kfa[cur], qfB, c2, 0, 0, 0);
        c3 = __builtin_amdgcn_mfma_f32_16x16x32_bf16(kfb[cur], qfB, c3, 0, 0, 0);

        // prefetch next step's K + bias (latency hidden behind exp2/LDS/PV)
        if (ks < 23) {
            const int k0n = k0 + 32;
            kfa[nxt] = *(const short8*)(const void*)(Kb + (k0n + lr) * HD + kc * 8);
            kfb[nxt] = *(const short8*)(const void*)(Kb + (k0n + 16 + lr) * HD + kc * 8);
            br0[nxt] = *(const uint2*)(const void*)(bt0 + (ks + 1) * 512);
            br1[nxt] = *(const uint2*)(const void*)(bt0 + (ks + 1) * 512 + 256);
            br2[nxt] = *(const uint2*)(const void*)(bt1 + (ks + 1) * 512);
            br3[nxt] = *(const uint2*)(const void*)(bt1 + (ks + 1) * 512 + 256);
        }
        // V for the current step
        short8 vf0 = *(const short8*)(const void*)(Vb + lr * VSTRIDE + k0 + kc * 8);
        short8 vf1 = *(const short8*)(const void*)(Vb + (lr + 16) * VSTRIDE + k0 + kc * 8);

        #pragma unroll
        for (int r = 0; r < 4; ++r) {
            c0[r] = fexp2(c0[r]); c1[r] = fexp2(c1[r]);
            c2[r] = fexp2(c2[r]); c3[r] = fexp2(c3[r]);
        }
        // P[q][key]: lane's 4 regs = 4 consecutive keys -> packed b64 writes
        pkstore(Pw + lr * PTS + kc * 4, c0);
        pkstore(Pw + lr * PTS + 16 + kc * 4, c1);
        pkstore(Pw + (16 + lr) * PTS + kc * 4, c2);
        pkstore(Pw + (16 + lr) * PTS + 16 + kc * 4, c3);
        asm volatile("" ::: "memory");
        __builtin_amdgcn_s_waitcnt(0xc07f);   // lgkmcnt(0); same-wave DS in order
        asm volatile("" ::: "memory");

        // A-frag: 8 consecutive keys at fixed q -> b128 reads
        short8 pfA = *(const short8*)(const void*)(Pw + lr * PTS + kc * 8);
        short8 pfB = *(const short8*)(const void*)(Pw + (16 + lr) * PTS + kc * 8);

        oa0 = __builtin_amdgcn_mfma_f32_16x16x32_bf16(pfA, vf0, oa0, 0, 0, 0);
        ob0 = __builtin_amdgcn_mfma_f32_16x16x32_bf16(pfA, vf1, ob0, 0, 0, 0);
        ol0 = __builtin_amdgcn_mfma_f32_16x16x32_bf16(pfA, onesf, ol0, 0, 0, 0);
        oa1 = __builtin_amdgcn_mfma_f32_16x16x32_bf16(pfB, vf0, oa1, 0, 0, 0);
        ob1 = __builtin_amdgcn_mfma_f32_16x16x32_bf16(pfB, vf1, ob1, 0, 0, 0);
        ol1 = __builtin_amdgcn_mfma_f32_16x16x32_bf16(pfB, onesf, ol1, 0, 0, 0);
    }

    #pragma unroll
    for (int r = 0; r < 4; ++r) {
        int row = kc * 4 + r;
        float lA = __shfl(ol0[r], lane & 48);
        float lB = __shfl(ol1[r], lane & 48);
        float liA = 1.0f / lA, liB = 1.0f / lB;
        int orA = q0 + row, orB = q0 + 16 + row;
        if (orA < NQ) {
            size_t base = ((size_t)b * NQ + orA) * CD + hh * HD;
            AO[base + lr]      = __hip_bfloat16(oa0[r] * liA);
            AO[base + 16 + lr] = __hip_bfloat16(ob0[r] * liA);
        }
        if (orB < NQ) {
            size_t base = ((size_t)b * NQ + orB) * CD + hh * HD;
            AO[base + lr]      = __hip_bfloat16(oa1[r] * liB);
            AO[base + 16 + lr] = __hip_bfloat16(ob1[r] * liB);
        }
    }
}

extern "C" void kernel_launch(void* const* d_in, const int* in_sizes, int n_in,
                              void* d_out, int out_size, void* d_ws, size_t ws_size,
                              hipStream_t stream) {
    char* ws = (char*)d_ws;
    size_t off = 0;
    auto carve = [&](size_t bytes) {
        char* p = ws + off;
        off += (bytes + 255) & ~(size_t)255;
        return p;
    };
    int* flagp = (int*)carve(256);
    __hip_bfloat16* Qw    = (__hip_bfloat16*)carve((size_t)256 * NQ * HD * 2);
    __hip_bfloat16* Kw    = (__hip_bfloat16*)carve((size_t)256 * NQ * HD * 2);
    __hip_bfloat16* Vtw   = (__hip_bfloat16*)carve((size_t)256 * HD * VSTRIDE * 2);
    __hip_bfloat16* WqT   = (__hip_bfloat16*)carve((size_t)1536 * 512 * 2);
    __hip_bfloat16* WpT   = (__hip_bfloat16*)carve((size_t)512 * 512 * 2);
    __hip_bfloat16* biasF = (__hip_bfloat16*)carve((size_t)16 * NQT * 48 * 64 * 4 * 2);
    __hip_bfloat16* Xb    = (__hip_bfloat16*)carve((size_t)MROWS * CD * 2);
    __hip_bfloat16* AO    = Xb;   // attn output overwrites x-staging (dead after qkv gemm)
    (void)ws_size; (void)in_sizes; (void)n_in; (void)out_size;

    sniff_k<<<dim3(1), dim3(64), 0, stream>>>((const unsigned int*)d_in[1], flagp);
    convx_k<<<dim3(5920), dim3(256), 0, stream>>>(d_in[0], (ushort4*)Xb, MROWS * CD / 4, flagp);
    transpose_k<<<dim3(48, 16), dim3(32, 8), 0, stream>>>(d_in[1], WqT, 512, 1536, flagp);
    transpose_k<<<dim3(16, 16), dim3(32, 8), 0, stream>>>(d_in[3], WpT, 512, 512, flagp);
    biasF_k<<<dim3(16 * NQT), dim3(256), 0, stream>>>(d_in[5], d_in[6], d_in[7], d_in[8],
                                                      d_in[9], d_in[10], biasF, flagp);
    gemm_qkv<<<dim3(12, 47), dim3(256), 0, stream>>>(Xb, WqT, d_in[2],
        Qw, Kw, Vtw, flagp);
    attn_k<<<dim3(6, 256), dim3(256), 0, stream>>>(Qw, Kw, Vtw, biasF, AO);
    gemm_bt<<<dim3(4, 93), dim3(256), 0, stream>>>(AO, WpT, d_in[4], MROWS,
        (__hip_bfloat16*)d_out, (float*)d_out, flagp);
}

// Round 11
// 252.082 us; speedup vs baseline: 1.3192x; 1.0886x over previous
//
#include <hip/hip_runtime.h>
#include <hip/hip_bf16.h>
#include <hip/hip_fp16.h>
#include <stdint.h>
#include <stddef.h>

typedef __attribute__((ext_vector_type(8))) short short8;
typedef __attribute__((ext_vector_type(4))) float f32x4;
typedef unsigned short ushort_t;

#define NHEADS 16
#define HD 32
#define NQ 740
#define NB 16
#define MROWS (NB*NQ)       // 11840
#define CD 512
#define KDIM 512
#define VSTRIDE 768         // v^T row stride
#define NQT 48              // padded q-tile slots for bias
#define PTS 40              // P[q][key] stride in bf16 (32 keys + 8 pad)
#define QS2 0.2550400865f   // hd^-0.5 * log2(e)
#define LOG2E 1.4426950409f
#define NEG_BIG -43000.0f   // log2e-scaled mask; v_exp_f32 flushes to 0

static __device__ __forceinline__ void gld_lds16(const void* g, void* l) {
    __builtin_amdgcn_global_load_lds((const __attribute__((address_space(1))) void*)g,
                                     (__attribute__((address_space(3))) void*)l,
                                     16, 0, 0);
}

static __device__ __forceinline__ float ldf(const void* p, int i, int fl) {
    return fl ? ((const float*)p)[i] : (float)((const __hip_bfloat16*)p)[i];
}
static __device__ __forceinline__ ushort_t f2bf(float f) {
    __hip_bfloat16 h(f);
    return *reinterpret_cast<ushort_t*>(&h);
}
static __device__ __forceinline__ float fexp2(float x) {
#if __has_builtin(__builtin_amdgcn_exp2f)
    return __builtin_amdgcn_exp2f(x);
#else
    return exp2f(x);
#endif
}
// f32 -> e5m2 byte (RNE via fp16; e5m2 == fp16 top byte)
static __device__ __forceinline__ unsigned int f2e5(float f) {
    __half h = __float2half(f);
    unsigned short hb = *reinterpret_cast<unsigned short*>(&h);
    return (((unsigned int)hb + 0x7fu + ((hb >> 8) & 1u)) >> 8) & 0xffu;
}
// 4 packed e5m2 -> f32x4 (byte<<8 = fp16 bits; HW cvt handles denorms)
static __device__ __forceinline__ f32x4 bias4f8(unsigned int b) {
    f32x4 c;
    #pragma unroll
    for (int i = 0; i < 4; ++i) {
        union { unsigned short u; __half h; } cv;
        cv.u = (unsigned short)(((b >> (8 * i)) & 0xffu) << 8);
        c[i] = __half2float(cv.h);
    }
    return c;
}
// pack f32x4 -> 4 bf16 (RNE, packed HW cvt), single 8B LDS store
static __device__ __forceinline__ void pkstore(__hip_bfloat16* dst, f32x4 c) {
    __hip_bfloat162* d = (__hip_bfloat162*)dst;
    d[0] = __float22bfloat162_rn(make_float2(c[0], c[1]));
    d[1] = __float22bfloat162_rn(make_float2(c[2], c[3]));
}
static __device__ __forceinline__ uint2 pk4(float a, float b, float c, float d) {
    __hip_bfloat162 p01 = __float22bfloat162_rn(make_float2(a, b));
    __hip_bfloat162 p23 = __float22bfloat162_rn(make_float2(c, d));
    uint2 u;
    u.x = *reinterpret_cast<unsigned int*>(&p01);
    u.y = *reinterpret_cast<unsigned int*>(&p23);
    return u;
}

// ------------- dtype sniff: fp32 arrays have uniform low-16 mantissa bits ----
__global__ __launch_bounds__(64) void sniff_k(const unsigned int* __restrict__ w,
                                              int* __restrict__ flag) {
    int cnt = 0;
    for (int i = threadIdx.x; i < 1024; i += 64) {
        unsigned int e = (w[i] >> 7) & 0xFFu;
        cnt += (e > 135u) ? 1 : 0;
    }
    #pragma unroll
    for (int d = 1; d < 64; d <<= 1) cnt += __shfl_xor(cnt, d);
    if (threadIdx.x == 0) *flag = (cnt > 16) ? 1 : 0;
}

// ------------- x normalization: fp32->bf16 (vectorized) or bf16 copy ---------
__global__ __launch_bounds__(256) void convx_k(const void* __restrict__ src,
                                               ushort4* __restrict__ dst,
                                               int nquads, const int* __restrict__ flag) {
    int i = blockIdx.x * 256 + threadIdx.x;
    if (i >= nquads) return;
    if (*flag) {
        float4 v = ((const float4*)src)[i];
        ushort4 o;
        o.x = f2bf(v.x); o.y = f2bf(v.y); o.z = f2bf(v.z); o.w = f2bf(v.w);
        dst[i] = o;
    } else {
        dst[i] = ((const ushort4*)src)[i];
    }
}

// ---------------- transpose + convert (for B^T weight layouts) ----------------
__global__ __launch_bounds__(256) void transpose_k(const void* __restrict__ src,
                                                   __hip_bfloat16* __restrict__ dst,
                                                   int R, int C, const int* __restrict__ flag) {
    __shared__ __hip_bfloat16 tile[32][33];
    const int fl = *flag;
    int bx = blockIdx.x * 32;   // col base in src
    int by = blockIdx.y * 32;   // row base in src
    int tx = threadIdx.x;
    for (int r = threadIdx.y; r < 32; r += 8)
        tile[r][tx] = __hip_bfloat16(ldf(src, (by + r) * C + bx + tx, fl));
    __syncthreads();
    for (int r = threadIdx.y; r < 32; r += 8)
        dst[(size_t)(bx + r) * R + by + tx] = tile[tx][r];
}

// -- bias * log2e, e5m2-packed, S^T fragment order: [blk=hh*48+qt][kb 48][lane 64]
__global__ __launch_bounds__(256) void biasF_k(
    const void* __restrict__ btT,    // bias_table_target [1849][16]
    const void* __restrict__ btt,    // bias_table_temp   [961][16]
    const void* __restrict__ ttab,   // temp_target_table [16][484]
    const void* __restrict__ tgtab,  // target_temp_table [16][256]
    const void* __restrict__ ttln,   // temp_target_line  [16][256]
    const void* __restrict__ tgln,   // target_temp_line  [16][484]
    unsigned int* __restrict__ biasF, const int* __restrict__ flag) {
    const int fl = *flag;
    const int blk = blockIdx.x;          // hh*48 + qt
    const int hh = blk / NQT;
    const int qt = blk - hh * NQT;
    for (int idx = threadIdx.x; idx < 48 * 64; idx += 256) {
        const int kb = idx >> 6;         // 16-key half-block
        const int lane = idx & 63;
        const int lr = lane & 15, kc = lane >> 4;
        int i = qt * 16 + lr; if (i > NQ - 1) i = NQ - 1;
        unsigned int pk = 0;
        #pragma unroll
        for (int r = 0; r < 4; ++r) {
            int c = kb * 16 + kc * 4 + r;
            float v;
            if (c >= NQ) {
                v = NEG_BIG;
            } else if (i < 256) {
                if (c < 256) {
                    int t = ((i >> 4) - (c >> 4) + 15) * 31 + ((i & 15) - (c & 15) + 15);
                    v = ldf(btt, t * 16 + hh, fl) * LOG2E;
                } else {
                    v = (ldf(tgtab, hh * 256 + i, fl) + ldf(tgln, hh * 484 + (c - 256), fl)) * LOG2E;
                }
            } else {
                int ii = i - 256;
                if (c < 256) {
                    v = (ldf(ttab, hh * 484 + ii, fl) + ldf(ttln, hh * 256 + c, fl)) * LOG2E;
                } else {
                    int jj = c - 256;
                    int a = ii / 22, b2 = ii - a * 22;
                    int a2 = jj / 22, b3 = jj - a2 * 22;
                    int t = (a - a2 + 21) * 43 + (b2 - b3 + 21);
                    v = ldf(btT, t * 16 + hh, fl) * LOG2E;
                }
            }
            pk |= f2e5(v) << (8 * r);
        }
        biasF[(size_t)blk * 48 * 64 + idx] = pk;
    }
}

// ------- qkv GEMM: 256x128 tile, n-fastest grid; LDS-repacked epilogue -------
__global__ __launch_bounds__(256) void gemm_qkv(
    const __hip_bfloat16* __restrict__ A,
    const __hip_bfloat16* __restrict__ Bt,
    const void* __restrict__ biasv,
    __hip_bfloat16* __restrict__ Qw,
    __hip_bfloat16* __restrict__ Kw,
    __hip_bfloat16* __restrict__ Vtw,
    const int* __restrict__ flag) {
    __shared__ __attribute__((aligned(16))) short sMem[256 * 32 + 128 * 32];  // 24 KB
    short* sA = sMem;                // 256x32
    short* sB = sMem + 256 * 32;     // 128x32
    const int tid = threadIdx.x;
    const int lane = tid & 63;
    const int wv = tid >> 6;             // 0..3: 64-row group
    const int lr = lane & 15, kc = lane >> 4;
    const int m0 = blockIdx.y * 256;     // y = m-block (slow)
    const int n0 = blockIdx.x * 128;     // x = n-block (fast) -> A-tile reuse
    const int fl = *flag;
    const int M = MROWS;

    f32x4 acc[4][8] = {};

    for (int k0 = 0; k0 < KDIM; k0 += 32) {
        #pragma unroll
        for (int it = 0; it < 6; ++it) {
            int idx = it * 256 + tid;            // 16B unit index, 0..1535
            if (idx < 1024) {                    // A: 256 rows x 4 units
                int r = idx >> 2, c = idx & 3;
                int gr = m0 + r; if (gr > M - 1) gr = M - 1;
                gld_lds16(A + (size_t)gr * KDIM + k0 + c * 8, (char*)sA + idx * 16);
            } else {                             // B: 128 rows x 4 units
                int u = idx - 1024;
                int r = u >> 2, c = u & 3;
                gld_lds16(Bt + (size_t)(n0 + r) * KDIM + k0 + c * 8, (char*)sB + u * 16);
            }
        }
        __syncthreads();
        short8 af[4], bfr[8];
        #pragma unroll
        for (int t = 0; t < 4; ++t)
            af[t] = *(const short8*)&sA[(wv * 64 + t * 16 + lr) * 32 + kc * 8];
        #pragma unroll
        for (int t = 0; t < 8; ++t)
            bfr[t] = *(const short8*)&sB[(t * 16 + lr) * 32 + kc * 8];
        #pragma unroll
        for (int i = 0; i < 4; ++i)
            #pragma unroll
            for (int j = 0; j < 8; ++j)
                acc[i][j] = __builtin_amdgcn_mfma_f32_16x16x32_bf16(af[i], bfr[j], acc[i][j], 0, 0, 0);
        __syncthreads();
    }

    // ---- epilogue: LDS repack -> coalesced global stores ----
    const int s = n0 >> 9;                      // 0:q 1:k 2:v, uniform per WG
    short* Tw = sMem + wv * 2560;               // per-wave 5KB scratch
    const int gmr = m0 + wv * 64 + lane;        // q/k: row this lane stores
    int gmrc = gmr < M ? gmr : M - 1;
    int bq = gmrc / NQ;
    int nnq = gmrc - bq * NQ;
    const int gmv = m0 + wv * 64 + (lane & 15) * 4;   // v: 4-row quad (740%4==0)
    int gmvc = gmv < M ? gmv : M - 1;
    int bv2 = gmvc / NQ;
    int nnv = gmvc - bv2 * NQ;

    #pragma unroll
    for (int t = 0; t < 4; ++t) {
        const int hh = ((n0 >> 5) + t) & 15;
        float bva = ldf(biasv, n0 + t * 32 + lr, fl);
        float bvb = ldf(biasv, n0 + t * 32 + 16 + lr, fl);
        asm volatile("" ::: "memory");
        if (s == 2) {
            #pragma unroll
            for (int i = 0; i < 4; ++i) {
                int nl = i * 16 + kc * 4;
                uint2 ua = pk4(acc[i][2*t][0] + bva, acc[i][2*t][1] + bva,
                               acc[i][2*t][2] + bva, acc[i][2*t][3] + bva);
                uint2 ub = pk4(acc[i][2*t+1][0] + bvb, acc[i][2*t+1][1] + bvb,
                               acc[i][2*t+1][2] + bvb, acc[i][2*t+1][3] + bvb);
                *(uint2*)(void*)&Tw[lr * 72 + nl]        = ua;
                *(uint2*)(void*)&Tw[(16 + lr) * 72 + nl] = ub;
            }
        } else {
            float sc = (s == 0) ? QS2 : 1.0f;
            #pragma unroll
            for (int i = 0; i < 4; ++i)
                #pragma unroll
                for (int r = 0; r < 4; ++r) {
                    int nl = i * 16 + kc * 4 + r;
                    Tw[nl * 40 + lr]      = (short)f2bf((acc[i][2*t][r]   + bva) * sc);
                    Tw[nl * 40 + 16 + lr] = (short)f2bf((acc[i][2*t+1][r] + bvb) * sc);
                }
        }
        asm volatile("" ::: "memory");
        __builtin_amdgcn_s_waitcnt(0xc07f);   // lgkmcnt(0); same-wave DS in order
        asm volatile("" ::: "memory");
        if (s == 2) {
            if (gmv < M) {
                size_t bh = (size_t)(bv2 * 16 + hh);
                #pragma unroll
                for (int i2 = 0; i2 < 8; ++i2) {
                    int d = (lane >> 4) + i2 * 4;
                    uint2 u = *(const uint2*)(const void*)&Tw[d * 72 + (lane & 15) * 4];
                    *(uint2*)(void*)(Vtw + (bh * HD + d) * VSTRIDE + nnv) = u;
                }
            }
        } else {
            if (gmr < M) {
                size_t bh = (size_t)(bq * 16 + hh);
                __hip_bfloat16* dst = (s == 0 ? Qw : Kw) + (bh * NQ + nnq) * HD;
                #pragma unroll
                for (int c = 0; c < 4; ++c) {
                    short8 u = *(const short8*)(const void*)&Tw[lane * 40 + c * 8];
                    *(short8*)(void*)(dst + c * 8) = u;
                }
            }
        }
        asm volatile("" ::: "memory");
        __builtin_amdgcn_s_waitcnt(0xc07f);
        asm volatile("" ::: "memory");
    }
}

// ----- m97-style 128x128 bf16 GEMM (proj), grid n-fastest: Out = A@Bt^T+bias -
__global__ __launch_bounds__(256) void gemm_bt(
    const __hip_bfloat16* __restrict__ A,
    const __hip_bfloat16* __restrict__ Bt,
    const void* __restrict__ biasv,
    int M,
    __hip_bfloat16* __restrict__ Out,
    float* __restrict__ OutF,
    const int* __restrict__ flag) {
    __shared__ __attribute__((aligned(16))) short sA[128 * 32];
    __shared__ __attribute__((aligned(16))) short sB[128 * 32];
    const int tid = threadIdx.x;
    const int lane = tid & 63;
    const int wv = tid >> 6;
    const int wr = wv >> 1, wc = wv & 1;
    const int lr = lane & 15, kc = lane >> 4;
    const int m0 = blockIdx.y * 128;     // y = m (slow)
    const int n0 = blockIdx.x * 128;     // x = n (fast) -> A-tile reuse
    const int fl = *flag;

    f32x4 acc[4][4] = {};

    for (int k0 = 0; k0 < KDIM; k0 += 32) {
        #pragma unroll
        for (int it = 0; it < 2; ++it) {
            int idx = it * 256 + tid;           // 16-byte unit index
            int r = idx >> 2;
            int c = idx & 3;
            int gr = m0 + r; if (gr > M - 1) gr = M - 1;
            gld_lds16(A + (size_t)gr * KDIM + k0 + c * 8, (char*)sA + idx * 16);
            gld_lds16(Bt + (size_t)(n0 + r) * KDIM + k0 + c * 8, (char*)sB + idx * 16);
        }
        __syncthreads();
        short8 af[4], bfr[4];
        #pragma unroll
        for (int t = 0; t < 4; ++t)
            af[t] = *(const short8*)&sA[(wr * 64 + t * 16 + lr) * 32 + kc * 8];
        #pragma unroll
        for (int t = 0; t < 4; ++t)
            bfr[t] = *(const short8*)&sB[(wc * 64 + t * 16 + lr) * 32 + kc * 8];
        #pragma unroll
        for (int i = 0; i < 4; ++i)
            #pragma unroll
            for (int j = 0; j < 4; ++j)
                acc[i][j] = __builtin_amdgcn_mfma_f32_16x16x32_bf16(af[i], bfr[j], acc[i][j], 0, 0, 0);
        __syncthreads();
    }

    #pragma unroll
    for (int i = 0; i < 4; ++i) {
        #pragma unroll
        for (int j = 0; j < 4; ++j) {
            int gn = n0 + wc * 64 + j * 16 + lr;
            float bv = ldf(biasv, gn, fl);
            #pragma unroll
            for (int r = 0; r < 4; ++r) {
                int gm = m0 + wr * 64 + i * 16 + kc * 4 + r;
                if (gm < M) {
                    float v = acc[i][j][r] + bv;
                    if (fl) OutF[(size_t)gm * CD + gn] = v;
                    else    Out[(size_t)gm * CD + gn] = __hip_bfloat16(v);
                }
            }
        }
    }
}

// ---- fused attention v8: WG-shared K/V DMA staging (3-buf, 1 barrier/step) --
// All 4 waves share bh -> K/V staged once per WG via global_load_lds. Raw
// s_barrier + vmcnt(5) (never vmcnt(0) mid-loop): stage(ks+1) stays in flight
// across the barrier. Bias = e5m2 fragment-order, register ping-pong prefetch.
__global__ __launch_bounds__(256) void attn_k(
    const __hip_bfloat16* __restrict__ Qw,
    const __hip_bfloat16* __restrict__ Kw,
    const __hip_bfloat16* __restrict__ Vtw,
    const unsigned int* __restrict__ biasF,
    __hip_bfloat16* __restrict__ AO) {
    __shared__ __attribute__((aligned(16))) short sStage[3 * 2048];        // 12 KB: 3 x (K 2KB + V 2KB)
    __shared__ __attribute__((aligned(16))) __hip_bfloat16 Pt[4][32 * PTS]; // 10 KB

    const int tid = threadIdx.x;
    const int wv = tid >> 6;
    const int pair = blockIdx.x * 4 + wv;    // 0..23 exactly
    const int bh = blockIdx.y;               // b*16 + h
    const int hh = bh & 15;
    const int b = bh >> 4;
    const int q0 = pair * 32;
    const int lane = tid & 63;
    const int lr = lane & 15, kc = lane >> 4;

    const __hip_bfloat16* Qb = Qw + (size_t)bh * NQ * HD;
    const __hip_bfloat16* Kb = Kw + (size_t)bh * NQ * HD;
    const __hip_bfloat16* Vb = Vtw + (size_t)bh * HD * VSTRIDE;
    __hip_bfloat16* Pw = &Pt[wv][0];

    short8 qfA = *(const short8*)(const void*)(Qb + (q0 + lr) * HD + kc * 8);
    short8 qfB = *(const short8*)(const void*)(Qb + (q0 + 16 + lr) * HD + kc * 8);

    short8 onesf;
    {
        short s1 = (lr == 0) ? (short)0x3F80 : (short)0;
        #pragma unroll
        for (int j = 0; j < 8; ++j) onesf[j] = s1;
    }

    // e5m2 fragment-order bias: [blk][kb 48][lane 64] uint
    const unsigned int* bt0 = biasF + (size_t)(hh * NQT + 2 * pair) * 48 * 64 + lane;
    const unsigned int* bt1 = bt0 + 48 * 64;

    unsigned int brA0[2], brA1[2], brB0[2], brB1[2];
    brA0[0] = bt0[0];  brA1[0] = bt0[64];
    brB0[0] = bt1[0];  brB1[0] = bt1[64];

    // per-thread staging source (k0 varies): K units 0..127, V units 128..255
    // prologue: stage(0) into buf 0
    {
        const void* src;
        if (tid < 128) src = Kb + (tid >> 2) * HD + (tid & 3) * 8;
        else { int u = tid - 128; src = Vb + (u >> 2) * VSTRIDE + (u & 3) * 8; }
        gld_lds16(src, (char*)sStage + tid * 16);
    }
    asm volatile("" ::: "memory");

    f32x4 oa0 = {}, ob0 = {}, ol0 = {};
    f32x4 oa1 = {}, ob1 = {}, ol1 = {};

    #pragma unroll
    for (int ks = 0; ks < 24; ++ks) {
        const int cur = ks & 1, nxt = cur ^ 1;
        if (ks < 23) {
            // bias prefetch first, then stage -> vmcnt(5) leaves exactly these 5 in flight
            brA0[nxt] = bt0[(2 * ks + 2) * 64];
            brA1[nxt] = bt0[(2 * ks + 3) * 64];
            brB0[nxt] = bt1[(2 * ks + 2) * 64];
            brB1[nxt] = bt1[(2 * ks + 3) * 64];
            const int k0n = (ks + 1) * 32;
            const int nb = ((ks + 1) % 3) * 4096;
            const void* src;
            if (tid < 128) src = Kb + (k0n + (tid >> 2)) * HD + (tid & 3) * 8;
            else { int u = tid - 128; src = Vb + (u >> 2) * VSTRIDE + k0n + (u & 3) * 8; }
            gld_lds16(src, (char*)sStage + nb + tid * 16);
        }
        asm volatile("" ::: "memory");
        if (ks < 23) __builtin_amdgcn_s_waitcnt(0x0F75);   // vmcnt(5): stage(ks) done
        else         __builtin_amdgcn_s_waitcnt(0x0F70);   // vmcnt(0): last stage done
        __builtin_amdgcn_s_barrier();
        asm volatile("" ::: "memory");

        const short* sK = (const short*)((const char*)sStage + (ks % 3) * 4096);
        const short* sV = sK + 1024;
        short8 kf0 = *(const short8*)&sK[lr * 32 + kc * 8];
        short8 kf1 = *(const short8*)&sK[(16 + lr) * 32 + kc * 8];
        short8 vf0 = *(const short8*)&sV[lr * 32 + kc * 8];
        short8 vf1 = *(const short8*)&sV[(16 + lr) * 32 + kc * 8];

        f32x4 c0 = bias4f8(brA0[cur]);
        f32x4 c1 = bias4f8(brA1[cur]);
        f32x4 c2 = bias4f8(brB0[cur]);
        f32x4 c3 = bias4f8(brB1[cur]);

        // S^T: D[key][q]
        c0 = __builtin_amdgcn_mfma_f32_16x16x32_bf16(kf0, qfA, c0, 0, 0, 0);
        c1 = __builtin_amdgcn_mfma_f32_16x16x32_bf16(kf1, qfA, c1, 0, 0, 0);
        c2 = __builtin_amdgcn_mfma_f32_16x16x32_bf16(kf0, qfB, c2, 0, 0, 0);
        c3 = __builtin_amdgcn_mfma_f32_16x16x32_bf16(kf1, qfB, c3, 0, 0, 0);

        #pragma unroll
        for (int r = 0; r < 4; ++r) {
            c0[r] = fexp2(c0[r]); c1[r] = fexp2(c1[r]);
            c2[r] = fexp2(c2[r]); c3[r] = fexp2(c3[r]);
        }
        // P[q][key]: lane's 4 regs = 4 consecutive keys -> packed b64 writes
        pkstore(Pw + lr * PTS + kc * 4, c0);
        pkstore(Pw + lr * PTS + 16 + kc * 4, c1);
        pkstore(Pw + (16 + lr) * PTS + kc * 4, c2);
        pkstore(Pw + (16 + lr) * PTS + 16 + kc * 4, c3);
        asm volatile("" ::: "memory");
        __builtin_amdgcn_s_waitcnt(0xc07f);   // lgkmcnt(0); same-wave DS in order
        asm volatile("" ::: "memory");

        short8 pfA = *(const short8*)(const void*)(Pw + lr * PTS + kc * 8);
        short8 pfB = *(const short8*)(const void*)(Pw + (16 + lr) * PTS + kc * 8);

        oa0 = __builtin_amdgcn_mfma_f32_16x16x32_bf16(pfA, vf0, oa0, 0, 0, 0);
        ob0 = __builtin_amdgcn_mfma_f32_16x16x32_bf16(pfA, vf1, ob0, 0, 0, 0);
        ol0 = __builtin_amdgcn_mfma_f32_16x16x32_bf16(pfA, onesf, ol0, 0, 0, 0);
        oa1 = __builtin_amdgcn_mfma_f32_16x16x32_bf16(pfB, vf0, oa1, 0, 0, 0);
        ob1 = __builtin_amdgcn_mfma_f32_16x16x32_bf16(pfB, vf1, ob1, 0, 0, 0);
        ol1 = __builtin_amdgcn_mfma_f32_16x16x32_bf16(pfB, onesf, ol1, 0, 0, 0);
    }

    #pragma unroll
    for (int r = 0; r < 4; ++r) {
        int row = kc * 4 + r;
        float lA = __shfl(ol0[r], lane & 48);
        float lB = __shfl(ol1[r], lane & 48);
        float liA = 1.0f / lA, liB = 1.0f / lB;
        int orA = q0 + row, orB = q0 + 16 + row;
        if (orA < NQ) {
            size_t base = ((size_t)b * NQ + orA) * CD + hh * HD;
            AO[base + lr]      = __hip_bfloat16(oa0[r] * liA);
            AO[base + 16 + lr] = __hip_bfloat16(ob0[r] * liA);
        }
        if (orB < NQ) {
            size_t base = ((size_t)b * NQ + orB) * CD + hh * HD;
            AO[base + lr]      = __hip_bfloat16(oa1[r] * liB);
            AO[base + 16 + lr] = __hip_bfloat16(ob1[r] * liB);
        }
    }
}

extern "C" void kernel_launch(void* const* d_in, const int* in_sizes, int n_in,
                              void* d_out, int out_size, void* d_ws, size_t ws_size,
                              hipStream_t stream) {
    char* ws = (char*)d_ws;
    size_t off = 0;
    auto carve = [&](size_t bytes) {
        char* p = ws + off;
        off += (bytes + 255) & ~(size_t)255;
        return p;
    };
    int* flagp = (int*)carve(256);
    __hip_bfloat16* Qw    = (__hip_bfloat16*)carve((size_t)256 * NQ * HD * 2);
    __hip_bfloat16* Kw    = (__hip_bfloat16*)carve((size_t)256 * NQ * HD * 2);
    __hip_bfloat16* Vtw   = (__hip_bfloat16*)carve((size_t)256 * HD * VSTRIDE * 2);
    __hip_bfloat16* WqT   = (__hip_bfloat16*)carve((size_t)1536 * 512 * 2);
    __hip_bfloat16* WpT   = (__hip_bfloat16*)carve((size_t)512 * 512 * 2);
    unsigned int*   biasF = (unsigned int*)carve((size_t)16 * NQT * 48 * 64 * 4);
    __hip_bfloat16* Xb    = (__hip_bfloat16*)carve((size_t)MROWS * CD * 2);
    __hip_bfloat16* AO    = Xb;   // attn output overwrites x-staging (dead after qkv gemm)
    (void)ws_size; (void)in_sizes; (void)n_in; (void)out_size;

    sniff_k<<<dim3(1), dim3(64), 0, stream>>>((const unsigned int*)d_in[1], flagp);
    convx_k<<<dim3(5920), dim3(256), 0, stream>>>(d_in[0], (ushort4*)Xb, MROWS * CD / 4, flagp);
    transpose_k<<<dim3(48, 16), dim3(32, 8), 0, stream>>>(d_in[1], WqT, 512, 1536, flagp);
    transpose_k<<<dim3(16, 16), dim3(32, 8), 0, stream>>>(d_in[3], WpT, 512, 512, flagp);
    biasF_k<<<dim3(16 * NQT), dim3(256), 0, stream>>>(d_in[5], d_in[6], d_in[7], d_in[8],
                                                      d_in[9], d_in[10], biasF, flagp);
    gemm_qkv<<<dim3(12, 47), dim3(256), 0, stream>>>(Xb, WqT, d_in[2],
        Qw, Kw, Vtw, flagp);
    attn_k<<<dim3(6, 256), dim3(256), 0, stream>>>(Qw, Kw, Vtw, biasF, AO);
    gemm_bt<<<dim3(4, 93), dim3(256), 0, stream>>>(AO, WpT, d_in[4], MROWS,
        (__hip_bfloat16*)d_out, (float*)d_out, flagp);
}

// Round 12
// 225.758 us; speedup vs baseline: 1.4730x; 1.1166x over previous
//
#include <hip/hip_runtime.h>
#include <hip/hip_bf16.h>
#include <hip/hip_fp16.h>
#include <stdint.h>
#include <stddef.h>

typedef __attribute__((ext_vector_type(8))) short short8;
typedef __attribute__((ext_vector_type(4))) float f32x4;
typedef unsigned short ushort_t;

#define NHEADS 16
#define HD 32
#define NQ 740
#define NB 16
#define MROWS (NB*NQ)       // 11840
#define CD 512
#define KDIM 512
#define VSTRIDE 768         // v^T row stride
#define NQT 48              // padded q-tile slots for bias
#define PTS 40              // P[q][key] stride in bf16 (32 keys + 8 pad)
#define QS2 0.2550400865f   // hd^-0.5 * log2(e)
#define LOG2E 1.4426950409f
#define NEG_BIG -43000.0f   // log2e-scaled mask; v_exp_f32 flushes to 0

static __device__ __forceinline__ void gld_lds16(const void* g, void* l) {
    __builtin_amdgcn_global_load_lds((const __attribute__((address_space(1))) void*)g,
                                     (__attribute__((address_space(3))) void*)l,
                                     16, 0, 0);
}

static __device__ __forceinline__ float ldf(const void* p, int i, int fl) {
    return fl ? ((const float*)p)[i] : (float)((const __hip_bfloat16*)p)[i];
}
static __device__ __forceinline__ ushort_t f2bf(float f) {
    __hip_bfloat16 h(f);
    return *reinterpret_cast<ushort_t*>(&h);
}
static __device__ __forceinline__ float fexp2(float x) {
#if __has_builtin(__builtin_amdgcn_exp2f)
    return __builtin_amdgcn_exp2f(x);
#else
    return exp2f(x);
#endif
}
// f32 -> e5m2 byte (RNE via fp16; e5m2 == fp16 top byte)
static __device__ __forceinline__ unsigned int f2e5(float f) {
    __half h = __float2half(f);
    unsigned short hb = *reinterpret_cast<unsigned short*>(&h);
    return (((unsigned int)hb + 0x7fu + ((hb >> 8) & 1u)) >> 8) & 0xffu;
}
// 4 packed e5m2 -> f32x4 (byte<<8 = fp16 bits; HW cvt handles denorms)
static __device__ __forceinline__ f32x4 bias4f8(unsigned int b) {
    f32x4 c;
    #pragma unroll
    for (int i = 0; i < 4; ++i) {
        union { unsigned short u; __half h; } cv;
        cv.u = (unsigned short)(((b >> (8 * i)) & 0xffu) << 8);
        c[i] = __half2float(cv.h);
    }
    return c;
}
// pack f32x4 -> 4 bf16 (RNE, packed HW cvt), single 8B LDS store
static __device__ __forceinline__ void pkstore(__hip_bfloat16* dst, f32x4 c) {
    __hip_bfloat162* d = (__hip_bfloat162*)dst;
    d[0] = __float22bfloat162_rn(make_float2(c[0], c[1]));
    d[1] = __float22bfloat162_rn(make_float2(c[2], c[3]));
}
static __device__ __forceinline__ uint2 pk4(float a, float b, float c, float d) {
    __hip_bfloat162 p01 = __float22bfloat162_rn(make_float2(a, b));
    __hip_bfloat162 p23 = __float22bfloat162_rn(make_float2(c, d));
    uint2 u;
    u.x = *reinterpret_cast<unsigned int*>(&p01);
    u.y = *reinterpret_cast<unsigned int*>(&p23);
    return u;
}

// ------------- dtype sniff: fp32 arrays have uniform low-16 mantissa bits ----
__global__ __launch_bounds__(64) void sniff_k(const unsigned int* __restrict__ w,
                                              int* __restrict__ flag) {
    int cnt = 0;
    for (int i = threadIdx.x; i < 1024; i += 64) {
        unsigned int e = (w[i] >> 7) & 0xFFu;
        cnt += (e > 135u) ? 1 : 0;
    }
    #pragma unroll
    for (int d = 1; d < 64; d <<= 1) cnt += __shfl_xor(cnt, d);
    if (threadIdx.x == 0) *flag = (cnt > 16) ? 1 : 0;
}

// ------------- x normalization: fp32->bf16 (vectorized) or bf16 copy ---------
__global__ __launch_bounds__(256) void convx_k(const void* __restrict__ src,
                                               ushort4* __restrict__ dst,
                                               int nquads, const int* __restrict__ flag) {
    int i = blockIdx.x * 256 + threadIdx.x;
    if (i >= nquads) return;
    if (*flag) {
        float4 v = ((const float4*)src)[i];
        ushort4 o;
        o.x = f2bf(v.x); o.y = f2bf(v.y); o.z = f2bf(v.z); o.w = f2bf(v.w);
        dst[i] = o;
    } else {
        dst[i] = ((const ushort4*)src)[i];
    }
}

// ---------------- transpose + convert (for B^T weight layouts) ----------------
__global__ __launch_bounds__(256) void transpose_k(const void* __restrict__ src,
                                                   __hip_bfloat16* __restrict__ dst,
                                                   int R, int C, const int* __restrict__ flag) {
    __shared__ __hip_bfloat16 tile[32][33];
    const int fl = *flag;
    int bx = blockIdx.x * 32;   // col base in src
    int by = blockIdx.y * 32;   // row base in src
    int tx = threadIdx.x;
    for (int r = threadIdx.y; r < 32; r += 8)
        tile[r][tx] = __hip_bfloat16(ldf(src, (by + r) * C + bx + tx, fl));
    __syncthreads();
    for (int r = threadIdx.y; r < 32; r += 8)
        dst[(size_t)(bx + r) * R + by + tx] = tile[tx][r];
}

// -- bias * log2e, e5m2-packed, S^T fragment order: [blk=hh*48+qt][kb 48][lane 64]
__global__ __launch_bounds__(256) void biasF_k(
    const void* __restrict__ btT,    // bias_table_target [1849][16]
    const void* __restrict__ btt,    // bias_table_temp   [961][16]
    const void* __restrict__ ttab,   // temp_target_table [16][484]
    const void* __restrict__ tgtab,  // target_temp_table [16][256]
    const void* __restrict__ ttln,   // temp_target_line  [16][256]
    const void* __restrict__ tgln,   // target_temp_line  [16][484]
    unsigned int* __restrict__ biasF, const int* __restrict__ flag) {
    const int fl = *flag;
    const int blk = blockIdx.x;          // hh*48 + qt
    const int hh = blk / NQT;
    const int qt = blk - hh * NQT;
    for (int idx = threadIdx.x; idx < 48 * 64; idx += 256) {
        const int kb = idx >> 6;         // 16-key half-block
        const int lane = idx & 63;
        const int lr = lane & 15, kc = lane >> 4;
        int i = qt * 16 + lr; if (i > NQ - 1) i = NQ - 1;
        unsigned int pk = 0;
        #pragma unroll
        for (int r = 0; r < 4; ++r) {
            int c = kb * 16 + kc * 4 + r;
            float v;
            if (c >= NQ) {
                v = NEG_BIG;
            } else if (i < 256) {
                if (c < 256) {
                    int t = ((i >> 4) - (c >> 4) + 15) * 31 + ((i & 15) - (c & 15) + 15);
                    v = ldf(btt, t * 16 + hh, fl) * LOG2E;
                } else {
                    v = (ldf(tgtab, hh * 256 + i, fl) + ldf(tgln, hh * 484 + (c - 256), fl)) * LOG2E;
                }
            } else {
                int ii = i - 256;
                if (c < 256) {
                    v = (ldf(ttab, hh * 484 + ii, fl) + ldf(ttln, hh * 256 + c, fl)) * LOG2E;
                } else {
                    int jj = c - 256;
                    int a = ii / 22, b2 = ii - a * 22;
                    int a2 = jj / 22, b3 = jj - a2 * 22;
                    int t = (a - a2 + 21) * 43 + (b2 - b3 + 21);
                    v = ldf(btT, t * 16 + hh, fl) * LOG2E;
                }
            }
            pk |= f2e5(v) << (8 * r);
        }
        biasF[(size_t)blk * 48 * 64 + idx] = pk;
    }
}

// ------- qkv GEMM: 256x128 tile, PIPELINED K-loop (3-buf, depth-2 prefetch) --
// One barrier/step with s_waitcnt vmcnt(6) lgkm(0) BEFORE it; stage issued
// AFTER the barrier (WAR-safe: that buffer's readers drained pre-barrier).
// Never vmcnt(0) mid-loop -> prefetch stays in flight across the barrier.
__global__ __launch_bounds__(256) void gemm_qkv(
    const __hip_bfloat16* __restrict__ A,
    const __hip_bfloat16* __restrict__ Bt,
    const void* __restrict__ biasv,
    __hip_bfloat16* __restrict__ Qw,
    __hip_bfloat16* __restrict__ Kw,
    __hip_bfloat16* __restrict__ Vtw,
    const int* __restrict__ flag) {
    __shared__ __attribute__((aligned(16))) short sStage[3 * 12288];  // 72 KB: 3 x (A 16KB + B 8KB)
    const int tid = threadIdx.x;
    const int lane = tid & 63;
    const int wv = tid >> 6;             // 0..3: 64-row group
    const int lr = lane & 15, kc = lane >> 4;
    const int m0 = blockIdx.y * 256;     // y = m-block (slow)
    const int n0 = blockIdx.x * 128;     // x = n-block (fast) -> A-tile reuse
    const int fl = *flag;
    const int M = MROWS;

    auto stage = [&](int s) {
        char* bb = (char*)sStage + (s % 3) * 24576;
        const int k0 = s * 32;
        #pragma unroll
        for (int it = 0; it < 6; ++it) {
            int idx = it * 256 + tid;            // 16B unit index, 0..1535
            if (idx < 1024) {                    // A: 256 rows x 4 units
                int r = idx >> 2, c = idx & 3;
                int gr = m0 + r; if (gr > M - 1) gr = M - 1;
                gld_lds16(A + (size_t)gr * KDIM + k0 + c * 8, bb + idx * 16);
            } else {                             // B: 128 rows x 4 units
                int u = idx - 1024;
                int r = u >> 2, c = u & 3;
                gld_lds16(Bt + (size_t)(n0 + r) * KDIM + k0 + c * 8, bb + 16384 + u * 16);
            }
        }
    };

    f32x4 acc[4][8] = {};
    stage(0);
    stage(1);

    for (int ks = 0; ks < 16; ++ks) {
        asm volatile("" ::: "memory");
        if (ks < 15) __builtin_amdgcn_s_waitcnt(0x0076);  // vmcnt(6) lgkm(0): stage(ks) done, my reads drained
        else         __builtin_amdgcn_s_waitcnt(0x0070);  // vmcnt(0) lgkm(0)
        __builtin_amdgcn_s_barrier();
        asm volatile("" ::: "memory");
        if (ks + 2 < 16) stage(ks + 2);

        const char* bb = (const char*)sStage + (ks % 3) * 24576;
        const short* cA = (const short*)bb;
        const short* cB = (const short*)(bb + 16384);
        short8 af[4], bfr[8];
        #pragma unroll
        for (int t = 0; t < 4; ++t)
            af[t] = *(const short8*)&cA[(wv * 64 + t * 16 + lr) * 32 + kc * 8];
        #pragma unroll
        for (int t = 0; t < 8; ++t)
            bfr[t] = *(const short8*)&cB[(t * 16 + lr) * 32 + kc * 8];
        #pragma unroll
        for (int i = 0; i < 4; ++i)
            #pragma unroll
            for (int j = 0; j < 8; ++j)
                acc[i][j] = __builtin_amdgcn_mfma_f32_16x16x32_bf16(af[i], bfr[j], acc[i][j], 0, 0, 0);
    }

    // ---- epilogue: LDS repack -> coalesced global stores ----
    // Tw in buffer 1 (last read at iter 13; all waves past barrier(15) by now,
    // only buffer-0 reads may still be in flight).
    const int s = n0 >> 9;                      // 0:q 1:k 2:v, uniform per WG
    short* Tw = (short*)((char*)sStage + 24576) + wv * 2560;   // per-wave 5KB
    const int gmr = m0 + wv * 64 + lane;        // q/k: row this lane stores
    int gmrc = gmr < M ? gmr : M - 1;
    int bq = gmrc / NQ;
    int nnq = gmrc - bq * NQ;
    const int gmv = m0 + wv * 64 + (lane & 15) * 4;   // v: 4-row quad (740%4==0)
    int gmvc = gmv < M ? gmv : M - 1;
    int bv2 = gmvc / NQ;
    int nnv = gmvc - bv2 * NQ;

    #pragma unroll
    for (int t = 0; t < 4; ++t) {
        const int hh = ((n0 >> 5) + t) & 15;
        float bva = ldf(biasv, n0 + t * 32 + lr, fl);
        float bvb = ldf(biasv, n0 + t * 32 + 16 + lr, fl);
        asm volatile("" ::: "memory");
        if (s == 2) {
            #pragma unroll
            for (int i = 0; i < 4; ++i) {
                int nl = i * 16 + kc * 4;
                uint2 ua = pk4(acc[i][2*t][0] + bva, acc[i][2*t][1] + bva,
                               acc[i][2*t][2] + bva, acc[i][2*t][3] + bva);
                uint2 ub = pk4(acc[i][2*t+1][0] + bvb, acc[i][2*t+1][1] + bvb,
                               acc[i][2*t+1][2] + bvb, acc[i][2*t+1][3] + bvb);
                *(uint2*)(void*)&Tw[lr * 72 + nl]        = ua;
                *(uint2*)(void*)&Tw[(16 + lr) * 72 + nl] = ub;
            }
        } else {
            float sc = (s == 0) ? QS2 : 1.0f;
            #pragma unroll
            for (int i = 0; i < 4; ++i)
                #pragma unroll
                for (int r = 0; r < 4; ++r) {
                    int nl = i * 16 + kc * 4 + r;
                    Tw[nl * 40 + lr]      = (short)f2bf((acc[i][2*t][r]   + bva) * sc);
                    Tw[nl * 40 + 16 + lr] = (short)f2bf((acc[i][2*t+1][r] + bvb) * sc);
                }
        }
        asm volatile("" ::: "memory");
        __builtin_amdgcn_s_waitcnt(0xc07f);   // lgkmcnt(0); same-wave DS in order
        asm volatile("" ::: "memory");
        if (s == 2) {
            if (gmv < M) {
                size_t bh = (size_t)(bv2 * 16 + hh);
                #pragma unroll
                for (int i2 = 0; i2 < 8; ++i2) {
                    int d = (lane >> 4) + i2 * 4;
                    uint2 u = *(const uint2*)(const void*)&Tw[d * 72 + (lane & 15) * 4];
                    *(uint2*)(void*)(Vtw + (bh * HD + d) * VSTRIDE + nnv) = u;
                }
            }
        } else {
            if (gmr < M) {
                size_t bh = (size_t)(bq * 16 + hh);
                __hip_bfloat16* dst = (s == 0 ? Qw : Kw) + (bh * NQ + nnq) * HD;
                #pragma unroll
                for (int c = 0; c < 4; ++c) {
                    short8 u = *(const short8*)(const void*)&Tw[lane * 40 + c * 8];
                    *(short8*)(void*)(dst + c * 8) = u;
                }
            }
        }
        asm volatile("" ::: "memory");
        __builtin_amdgcn_s_waitcnt(0xc07f);
        asm volatile("" ::: "memory");
    }
}

// ----- proj GEMM: 128x128, PIPELINED K-loop (3-buf, depth-2): Out=A@Bt^T+bias
__global__ __launch_bounds__(256) void gemm_bt(
    const __hip_bfloat16* __restrict__ A,
    const __hip_bfloat16* __restrict__ Bt,
    const void* __restrict__ biasv,
    int M,
    __hip_bfloat16* __restrict__ Out,
    float* __restrict__ OutF,
    const int* __restrict__ flag) {
    __shared__ __attribute__((aligned(16))) short sStage[3 * 8192];   // 48 KB: 3 x (A 8KB + B 8KB)
    const int tid = threadIdx.x;
    const int lane = tid & 63;
    const int wv = tid >> 6;
    const int wr = wv >> 1, wc = wv & 1;
    const int lr = lane & 15, kc = lane >> 4;
    const int m0 = blockIdx.y * 128;     // y = m (slow)
    const int n0 = blockIdx.x * 128;     // x = n (fast) -> A-tile reuse
    const int fl = *flag;

    auto stage = [&](int s) {
        char* bb = (char*)sStage + (s % 3) * 16384;
        const int k0 = s * 32;
        #pragma unroll
        for (int it = 0; it < 2; ++it) {
            int idx = it * 256 + tid;           // 16-byte unit index
            int r = idx >> 2;
            int c = idx & 3;
            int gr = m0 + r; if (gr > M - 1) gr = M - 1;
            gld_lds16(A + (size_t)gr * KDIM + k0 + c * 8, bb + idx * 16);
            gld_lds16(Bt + (size_t)(n0 + r) * KDIM + k0 + c * 8, bb + 8192 + idx * 16);
        }
    };

    f32x4 acc[4][4] = {};
    stage(0);
    stage(1);

    for (int ks = 0; ks < 16; ++ks) {
        asm volatile("" ::: "memory");
        if (ks < 15) __builtin_amdgcn_s_waitcnt(0x0074);  // vmcnt(4) lgkm(0)
        else         __builtin_amdgcn_s_waitcnt(0x0070);  // vmcnt(0) lgkm(0)
        __builtin_amdgcn_s_barrier();
        asm volatile("" ::: "memory");
        if (ks + 2 < 16) stage(ks + 2);

        const char* bb = (const char*)sStage + (ks % 3) * 16384;
        const short* cA = (const short*)bb;
        const short* cB = (const short*)(bb + 8192);
        short8 af[4], bfr[4];
        #pragma unroll
        for (int t = 0; t < 4; ++t)
            af[t] = *(const short8*)&cA[(wr * 64 + t * 16 + lr) * 32 + kc * 8];
        #pragma unroll
        for (int t = 0; t < 4; ++t)
            bfr[t] = *(const short8*)&cB[(wc * 64 + t * 16 + lr) * 32 + kc * 8];
        #pragma unroll
        for (int i = 0; i < 4; ++i)
            #pragma unroll
            for (int j = 0; j < 4; ++j)
                acc[i][j] = __builtin_amdgcn_mfma_f32_16x16x32_bf16(af[i], bfr[j], acc[i][j], 0, 0, 0);
    }

    #pragma unroll
    for (int i = 0; i < 4; ++i) {
        #pragma unroll
        for (int j = 0; j < 4; ++j) {
            int gn = n0 + wc * 64 + j * 16 + lr;
            float bv = ldf(biasv, gn, fl);
            #pragma unroll
            for (int r = 0; r < 4; ++r) {
                int gm = m0 + wr * 64 + i * 16 + kc * 4 + r;
                if (gm < M) {
                    float v = acc[i][j][r] + bv;
                    if (fl) OutF[(size_t)gm * CD + gn] = v;
                    else    Out[(size_t)gm * CD + gn] = __hip_bfloat16(v);
                }
            }
        }
    }
}

// ---- fused attention v8: WG-shared K/V DMA staging (3-buf, 1 barrier/step) --
__global__ __launch_bounds__(256) void attn_k(
    const __hip_bfloat16* __restrict__ Qw,
    const __hip_bfloat16* __restrict__ Kw,
    const __hip_bfloat16* __restrict__ Vtw,
    const unsigned int* __restrict__ biasF,
    __hip_bfloat16* __restrict__ AO) {
    __shared__ __attribute__((aligned(16))) short sStage[3 * 2048];        // 12 KB
    __shared__ __attribute__((aligned(16))) __hip_bfloat16 Pt[4][32 * PTS]; // 10 KB

    const int tid = threadIdx.x;
    const int wv = tid >> 6;
    const int pair = blockIdx.x * 4 + wv;    // 0..23 exactly
    const int bh = blockIdx.y;               // b*16 + h
    const int hh = bh & 15;
    const int b = bh >> 4;
    const int q0 = pair * 32;
    const int lane = tid & 63;
    const int lr = lane & 15, kc = lane >> 4;

    const __hip_bfloat16* Qb = Qw + (size_t)bh * NQ * HD;
    const __hip_bfloat16* Kb = Kw + (size_t)bh * NQ * HD;
    const __hip_bfloat16* Vb = Vtw + (size_t)bh * HD * VSTRIDE;
    __hip_bfloat16* Pw = &Pt[wv][0];

    short8 qfA = *(const short8*)(const void*)(Qb + (q0 + lr) * HD + kc * 8);
    short8 qfB = *(const short8*)(const void*)(Qb + (q0 + 16 + lr) * HD + kc * 8);

    short8 onesf;
    {
        short s1 = (lr == 0) ? (short)0x3F80 : (short)0;
        #pragma unroll
        for (int j = 0; j < 8; ++j) onesf[j] = s1;
    }

    const unsigned int* bt0 = biasF + (size_t)(hh * NQT + 2 * pair) * 48 * 64 + lane;
    const unsigned int* bt1 = bt0 + 48 * 64;

    unsigned int brA0[2], brA1[2], brB0[2], brB1[2];
    brA0[0] = bt0[0];  brA1[0] = bt0[64];
    brB0[0] = bt1[0];  brB1[0] = bt1[64];

    {
        const void* src;
        if (tid < 128) src = Kb + (tid >> 2) * HD + (tid & 3) * 8;
        else { int u = tid - 128; src = Vb + (u >> 2) * VSTRIDE + (u & 3) * 8; }
        gld_lds16(src, (char*)sStage + tid * 16);
    }
    asm volatile("" ::: "memory");

    f32x4 oa0 = {}, ob0 = {}, ol0 = {};
    f32x4 oa1 = {}, ob1 = {}, ol1 = {};

    #pragma unroll
    for (int ks = 0; ks < 24; ++ks) {
        const int cur = ks & 1, nxt = cur ^ 1;
        if (ks < 23) {
            brA0[nxt] = bt0[(2 * ks + 2) * 64];
            brA1[nxt] = bt0[(2 * ks + 3) * 64];
            brB0[nxt] = bt1[(2 * ks + 2) * 64];
            brB1[nxt] = bt1[(2 * ks + 3) * 64];
            const int k0n = (ks + 1) * 32;
            const int nb = ((ks + 1) % 3) * 4096;
            const void* src;
            if (tid < 128) src = Kb + (k0n + (tid >> 2)) * HD + (tid & 3) * 8;
            else { int u = tid - 128; src = Vb + (u >> 2) * VSTRIDE + k0n + (u & 3) * 8; }
            gld_lds16(src, (char*)sStage + nb + tid * 16);
        }
        asm volatile("" ::: "memory");
        if (ks < 23) __builtin_amdgcn_s_waitcnt(0x0F75);   // vmcnt(5): stage(ks) done
        else         __builtin_amdgcn_s_waitcnt(0x0F70);   // vmcnt(0)
        __builtin_amdgcn_s_barrier();
        asm volatile("" ::: "memory");

        const short* sK = (const short*)((const char*)sStage + (ks % 3) * 4096);
        const short* sV = sK + 1024;
        short8 kf0 = *(const short8*)&sK[lr * 32 + kc * 8];
        short8 kf1 = *(const short8*)&sK[(16 + lr) * 32 + kc * 8];
        short8 vf0 = *(const short8*)&sV[lr * 32 + kc * 8];
        short8 vf1 = *(const short8*)&sV[(16 + lr) * 32 + kc * 8];

        f32x4 c0 = bias4f8(brA0[cur]);
        f32x4 c1 = bias4f8(brA1[cur]);
        f32x4 c2 = bias4f8(brB0[cur]);
        f32x4 c3 = bias4f8(brB1[cur]);

        c0 = __builtin_amdgcn_mfma_f32_16x16x32_bf16(kf0, qfA, c0, 0, 0, 0);
        c1 = __builtin_amdgcn_mfma_f32_16x16x32_bf16(kf1, qfA, c1, 0, 0, 0);
        c2 = __builtin_amdgcn_mfma_f32_16x16x32_bf16(kf0, qfB, c2, 0, 0, 0);
        c3 = __builtin_amdgcn_mfma_f32_16x16x32_bf16(kf1, qfB, c3, 0, 0, 0);

        #pragma unroll
        for (int r = 0; r < 4; ++r) {
            c0[r] = fexp2(c0[r]); c1[r] = fexp2(c1[r]);
            c2[r] = fexp2(c2[r]); c3[r] = fexp2(c3[r]);
        }
        pkstore(Pw + lr * PTS + kc * 4, c0);
        pkstore(Pw + lr * PTS + 16 + kc * 4, c1);
        pkstore(Pw + (16 + lr) * PTS + kc * 4, c2);
        pkstore(Pw + (16 + lr) * PTS + 16 + kc * 4, c3);
        asm volatile("" ::: "memory");
        __builtin_amdgcn_s_waitcnt(0xc07f);   // lgkmcnt(0); same-wave DS in order
        asm volatile("" ::: "memory");

        short8 pfA = *(const short8*)(const void*)(Pw + lr * PTS + kc * 8);
        short8 pfB = *(const short8*)(const void*)(Pw + (16 + lr) * PTS + kc * 8);

        oa0 = __builtin_amdgcn_mfma_f32_16x16x32_bf16(pfA, vf0, oa0, 0, 0, 0);
        ob0 = __builtin_amdgcn_mfma_f32_16x16x32_bf16(pfA, vf1, ob0, 0, 0, 0);
        ol0 = __builtin_amdgcn_mfma_f32_16x16x32_bf16(pfA, onesf, ol0, 0, 0, 0);
        oa1 = __builtin_amdgcn_mfma_f32_16x16x32_bf16(pfB, vf0, oa1, 0, 0, 0);
        ob1 = __builtin_amdgcn_mfma_f32_16x16x32_bf16(pfB, vf1, ob1, 0, 0, 0);
        ol1 = __builtin_amdgcn_mfma_f32_16x16x32_bf16(pfB, onesf, ol1, 0, 0, 0);
    }

    #pragma unroll
    for (int r = 0; r < 4; ++r) {
        int row = kc * 4 + r;
        float lA = __shfl(ol0[r], lane & 48);
        float lB = __shfl(ol1[r], lane & 48);
        float liA = 1.0f / lA, liB = 1.0f / lB;
        int orA = q0 + row, orB = q0 + 16 + row;
        if (orA < NQ) {
            size_t base = ((size_t)b * NQ + orA) * CD + hh * HD;
            AO[base + lr]      = __hip_bfloat16(oa0[r] * liA);
            AO[base + 16 + lr] = __hip_bfloat16(ob0[r] * liA);
        }
        if (orB < NQ) {
            size_t base = ((size_t)b * NQ + orB) * CD + hh * HD;
            AO[base + lr]      = __hip_bfloat16(oa1[r] * liB);
            AO[base + 16 + lr] = __hip_bfloat16(ob1[r] * liB);
        }
    }
}

extern "C" void kernel_launch(void* const* d_in, const int* in_sizes, int n_in,
                              void* d_out, int out_size, void* d_ws, size_t ws_size,
                              hipStream_t stream) {
    char* ws = (char*)d_ws;
    size_t off = 0;
    auto carve = [&](size_t bytes) {
        char* p = ws + off;
        off += (bytes + 255) & ~(size_t)255;
        return p;
    };
    int* flagp = (int*)carve(256);
    __hip_bfloat16* Qw    = (__hip_bfloat16*)carve((size_t)256 * NQ * HD * 2);
    __hip_bfloat16* Kw    = (__hip_bfloat16*)carve((size_t)256 * NQ * HD * 2);
    __hip_bfloat16* Vtw   = (__hip_bfloat16*)carve((size_t)256 * HD * VSTRIDE * 2);
    __hip_bfloat16* WqT   = (__hip_bfloat16*)carve((size_t)1536 * 512 * 2);
    __hip_bfloat16* WpT   = (__hip_bfloat16*)carve((size_t)512 * 512 * 2);
    unsigned int*   biasF = (unsigned int*)carve((size_t)16 * NQT * 48 * 64 * 4);
    __hip_bfloat16* Xb    = (__hip_bfloat16*)carve((size_t)MROWS * CD * 2);
    __hip_bfloat16* AO    = Xb;   // attn output overwrites x-staging (dead after qkv gemm)
    (void)ws_size; (void)in_sizes; (void)n_in; (void)out_size;

    sniff_k<<<dim3(1), dim3(64), 0, stream>>>((const unsigned int*)d_in[1], flagp);
    convx_k<<<dim3(5920), dim3(256), 0, stream>>>(d_in[0], (ushort4*)Xb, MROWS * CD / 4, flagp);
    transpose_k<<<dim3(48, 16), dim3(32, 8), 0, stream>>>(d_in[1], WqT, 512, 1536, flagp);
    transpose_k<<<dim3(16, 16), dim3(32, 8), 0, stream>>>(d_in[3], WpT, 512, 512, flagp);
    biasF_k<<<dim3(16 * NQT), dim3(256), 0, stream>>>(d_in[5], d_in[6], d_in[7], d_in[8],
                                                      d_in[9], d_in[10], biasF, flagp);
    gemm_qkv<<<dim3(12, 47), dim3(256), 0, stream>>>(Xb, WqT, d_in[2],
        Qw, Kw, Vtw, flagp);
    attn_k<<<dim3(6, 256), dim3(256), 0, stream>>>(Qw, Kw, Vtw, biasF, AO);
    gemm_bt<<<dim3(4, 93), dim3(256), 0, stream>>>(AO, WpT, d_in[4], MROWS,
        (__hip_bfloat16*)d_out, (float*)d_out, flagp);
}

// Round 13
// 222.008 us; speedup vs baseline: 1.4979x; 1.0169x over previous
//
#include <hip/hip_runtime.h>
#include <hip/hip_bf16.h>
#include <hip/hip_fp16.h>
#include <stdint.h>
#include <stddef.h>

typedef __attribute__((ext_vector_type(8))) short short8;
typedef __attribute__((ext_vector_type(4))) float f32x4;
typedef __attribute__((ext_vector_type(2))) float f32x2;
typedef unsigned short ushort_t;

#define NHEADS 16
#define HD 32
#define NQ 740
#define NB 16
#define MROWS (NB*NQ)       // 11840
#define CD 512
#define KDIM 512
#define VSTRIDE 768         // v^T row stride
#define NQT 48              // padded q-tile slots for bias
#define PTS 40              // P[q][key] stride in bf16 (32 keys + 8 pad)
#define QS2 0.2550400865f   // hd^-0.5 * log2(e)
#define LOG2E 1.4426950409f
#define NEG_BIG -43000.0f   // log2e-scaled mask; v_exp_f32 flushes to 0

static __device__ __forceinline__ void gld_lds16(const void* g, void* l) {
    __builtin_amdgcn_global_load_lds((const __attribute__((address_space(1))) void*)g,
                                     (__attribute__((address_space(3))) void*)l,
                                     16, 0, 0);
}

static __device__ __forceinline__ float ldf(const void* p, int i, int fl) {
    return fl ? ((const float*)p)[i] : (float)((const __hip_bfloat16*)p)[i];
}
static __device__ __forceinline__ ushort_t f2bf(float f) {
    __hip_bfloat16 h(f);
    return *reinterpret_cast<ushort_t*>(&h);
}
static __device__ __forceinline__ float fexp2(float x) {
#if __has_builtin(__builtin_amdgcn_exp2f)
    return __builtin_amdgcn_exp2f(x);
#else
    return exp2f(x);
#endif
}
// f32 -> e5m2 byte (RNE via fp16; e5m2 == fp16 top byte)
static __device__ __forceinline__ unsigned int f2e5(float f) {
    __half h = __float2half(f);
    unsigned short hb = *reinterpret_cast<unsigned short*>(&h);
    return (((unsigned int)hb + 0x7fu + ((hb >> 8) & 1u)) >> 8) & 0xffu;
}
// 4 packed e5m2 -> f32x4. gfx950: HW v_cvt_pk_f32_bf8 (OCP e5m2 == fp16 top byte)
#if __has_builtin(__builtin_amdgcn_cvt_pk_f32_bf8)
static __device__ __forceinline__ f32x4 bias4f8(unsigned int b) {
    f32x2 lo = __builtin_amdgcn_cvt_pk_f32_bf8((int)b, false);
    f32x2 hi = __builtin_amdgcn_cvt_pk_f32_bf8((int)b, true);
    f32x4 c;
    c[0] = lo[0]; c[1] = lo[1]; c[2] = hi[0]; c[3] = hi[1];
    return c;
}
#else
static __device__ __forceinline__ f32x4 bias4f8(unsigned int b) {
    f32x4 c;
    #pragma unroll
    for (int i = 0; i < 4; ++i) {
        union { unsigned short u; __half h; } cv;
        cv.u = (unsigned short)(((b >> (8 * i)) & 0xffu) << 8);
        c[i] = __half2float(cv.h);
    }
    return c;
}
#endif
// pack f32x4 -> 4 bf16 (RNE, packed HW cvt), single 8B LDS store
static __device__ __forceinline__ void pkstore(__hip_bfloat16* dst, f32x4 c) {
    __hip_bfloat162* d = (__hip_bfloat162*)dst;
    d[0] = __float22bfloat162_rn(make_float2(c[0], c[1]));
    d[1] = __float22bfloat162_rn(make_float2(c[2], c[3]));
}
static __device__ __forceinline__ uint2 pk4(float a, float b, float c, float d) {
    __hip_bfloat162 p01 = __float22bfloat162_rn(make_float2(a, b));
    __hip_bfloat162 p23 = __float22bfloat162_rn(make_float2(c, d));
    uint2 u;
    u.x = *reinterpret_cast<unsigned int*>(&p01);
    u.y = *reinterpret_cast<unsigned int*>(&p23);
    return u;
}

// ------------- dtype sniff: fp32 arrays have uniform low-16 mantissa bits ----
__global__ __launch_bounds__(64) void sniff_k(const unsigned int* __restrict__ w,
                                              int* __restrict__ flag) {
    int cnt = 0;
    for (int i = threadIdx.x; i < 1024; i += 64) {
        unsigned int e = (w[i] >> 7) & 0xFFu;
        cnt += (e > 135u) ? 1 : 0;
    }
    #pragma unroll
    for (int d = 1; d < 64; d <<= 1) cnt += __shfl_xor(cnt, d);
    if (threadIdx.x == 0) *flag = (cnt > 16) ? 1 : 0;
}

// ------- merged prep: convx | transpose Wqkv | transpose Wproj | biasF -------
// All bodies read only kernel inputs -> no cross-deps; one launch replaces 4.
#define PREP_CONV 1480
#define PREP_TA   768     // Wqkv transpose: 48 x 16
#define PREP_TB   256     // Wproj transpose: 16 x 16
#define PREP_BIAS 768     // biasF: 16*48
__global__ __launch_bounds__(256) void prep_k(
    const void* __restrict__ x, ushort4* __restrict__ Xb,
    const void* __restrict__ Wqkv, __hip_bfloat16* __restrict__ WqT,
    const void* __restrict__ Wproj, __hip_bfloat16* __restrict__ WpT,
    const void* __restrict__ btT, const void* __restrict__ btt,
    const void* __restrict__ ttab, const void* __restrict__ tgtab,
    const void* __restrict__ ttln, const void* __restrict__ tgln,
    unsigned int* __restrict__ biasF,
    const int* __restrict__ flag) {
    __shared__ __hip_bfloat16 tile[32][33];
    const int bid = blockIdx.x;
    const int tid = threadIdx.x;
    const int fl = *flag;

    if (bid < PREP_CONV) {
        const int n = MROWS * CD / 4;
        for (int i = bid * 256 + tid; i < n; i += PREP_CONV * 256) {
            if (fl) {
                float4 v = ((const float4*)x)[i];
                ushort4 o;
                o.x = f2bf(v.x); o.y = f2bf(v.y); o.z = f2bf(v.z); o.w = f2bf(v.w);
                Xb[i] = o;
            } else {
                Xb[i] = ((const ushort4*)x)[i];
            }
        }
        return;
    }
    if (bid < PREP_CONV + PREP_TA + PREP_TB) {
        const void* src; __hip_bfloat16* dst; int R, C, lb;
        if (bid < PREP_CONV + PREP_TA) {
            src = Wqkv; dst = WqT; R = 512; C = 1536; lb = bid - PREP_CONV;
        } else {
            src = Wproj; dst = WpT; R = 512; C = 512; lb = bid - PREP_CONV - PREP_TA;
        }
        int nbx = C / 32;
        int bx = (lb % nbx) * 32;
        int by = (lb / nbx) * 32;
        int tx = tid & 31, ty = tid >> 5;
        for (int r = ty; r < 32; r += 8)
            tile[r][tx] = __hip_bfloat16(ldf(src, (by + r) * C + bx + tx, fl));
        __syncthreads();
        for (int r = ty; r < 32; r += 8)
            dst[(size_t)(bx + r) * R + by + tx] = tile[tx][r];
        return;
    }
    // biasF: [blk=hh*48+qt][kb 48][lane 64] e5m2-packed uint
    const int blk = bid - (PREP_CONV + PREP_TA + PREP_TB);
    const int hh = blk / NQT;
    const int qt = blk - hh * NQT;
    for (int idx = tid; idx < 48 * 64; idx += 256) {
        const int lane = idx & 63;
        const int kb = idx >> 6;
        const int lr = lane & 15, kc = lane >> 4;
        int i = qt * 16 + lr; if (i > NQ - 1) i = NQ - 1;
        unsigned int pk = 0;
        #pragma unroll
        for (int r = 0; r < 4; ++r) {
            int c = kb * 16 + kc * 4 + r;
            float v;
            if (c >= NQ) {
                v = NEG_BIG;
            } else if (i < 256) {
                if (c < 256) {
                    int t = ((i >> 4) - (c >> 4) + 15) * 31 + ((i & 15) - (c & 15) + 15);
                    v = ldf(btt, t * 16 + hh, fl) * LOG2E;
                } else {
                    v = (ldf(tgtab, hh * 256 + i, fl) + ldf(tgln, hh * 484 + (c - 256), fl)) * LOG2E;
                }
            } else {
                int ii = i - 256;
                if (c < 256) {
                    v = (ldf(ttab, hh * 484 + ii, fl) + ldf(ttln, hh * 256 + c, fl)) * LOG2E;
                } else {
                    int jj = c - 256;
                    int a = ii / 22, b2 = ii - a * 22;
                    int a2 = jj / 22, b3 = jj - a2 * 22;
                    int t = (a - a2 + 21) * 43 + (b2 - b3 + 21);
                    v = ldf(btT, t * 16 + hh, fl) * LOG2E;
                }
            }
            pk |= f2e5(v) << (8 * r);
        }
        biasF[(size_t)blk * 48 * 64 + idx] = pk;
    }
}

// ------- qkv GEMM: 256x128 tile, PIPELINED K-loop (3-buf, depth-2 prefetch) --
__global__ __launch_bounds__(256) void gemm_qkv(
    const __hip_bfloat16* __restrict__ A,
    const __hip_bfloat16* __restrict__ Bt,
    const void* __restrict__ biasv,
    __hip_bfloat16* __restrict__ Qw,
    __hip_bfloat16* __restrict__ Kw,
    __hip_bfloat16* __restrict__ Vtw,
    const int* __restrict__ flag) {
    __shared__ __attribute__((aligned(16))) short sStage[3 * 12288];  // 72 KB
    const int tid = threadIdx.x;
    const int lane = tid & 63;
    const int wv = tid >> 6;
    const int lr = lane & 15, kc = lane >> 4;
    const int m0 = blockIdx.y * 256;
    const int n0 = blockIdx.x * 128;
    const int fl = *flag;
    const int M = MROWS;

    auto stage = [&](int s) {
        char* bb = (char*)sStage + (s % 3) * 24576;
        const int k0 = s * 32;
        #pragma unroll
        for (int it = 0; it < 6; ++it) {
            int idx = it * 256 + tid;
            if (idx < 1024) {
                int r = idx >> 2, c = idx & 3;
                int gr = m0 + r; if (gr > M - 1) gr = M - 1;
                gld_lds16(A + (size_t)gr * KDIM + k0 + c * 8, bb + idx * 16);
            } else {
                int u = idx - 1024;
                int r = u >> 2, c = u & 3;
                gld_lds16(Bt + (size_t)(n0 + r) * KDIM + k0 + c * 8, bb + 16384 + u * 16);
            }
        }
    };

    f32x4 acc[4][8] = {};
    stage(0);
    stage(1);

    for (int ks = 0; ks < 16; ++ks) {
        asm volatile("" ::: "memory");
        if (ks < 15) __builtin_amdgcn_s_waitcnt(0x0076);  // vmcnt(6) lgkm(0)
        else         __builtin_amdgcn_s_waitcnt(0x0070);
        __builtin_amdgcn_s_barrier();
        asm volatile("" ::: "memory");
        if (ks + 2 < 16) stage(ks + 2);

        const char* bb = (const char*)sStage + (ks % 3) * 24576;
        const short* cA = (const short*)bb;
        const short* cB = (const short*)(bb + 16384);
        short8 af[4], bfr[8];
        #pragma unroll
        for (int t = 0; t < 4; ++t)
            af[t] = *(const short8*)&cA[(wv * 64 + t * 16 + lr) * 32 + kc * 8];
        #pragma unroll
        for (int t = 0; t < 8; ++t)
            bfr[t] = *(const short8*)&cB[(t * 16 + lr) * 32 + kc * 8];
        #pragma unroll
        for (int i = 0; i < 4; ++i)
            #pragma unroll
            for (int j = 0; j < 8; ++j)
                acc[i][j] = __builtin_amdgcn_mfma_f32_16x16x32_bf16(af[i], bfr[j], acc[i][j], 0, 0, 0);
    }

    // ---- epilogue: LDS repack (buffer 1) -> coalesced global stores ----
    const int s = n0 >> 9;
    short* Tw = (short*)((char*)sStage + 24576) + wv * 2560;
    const int gmr = m0 + wv * 64 + lane;
    int gmrc = gmr < M ? gmr : M - 1;
    int bq = gmrc / NQ;
    int nnq = gmrc - bq * NQ;
    const int gmv = m0 + wv * 64 + (lane & 15) * 4;
    int gmvc = gmv < M ? gmv : M - 1;
    int bv2 = gmvc / NQ;
    int nnv = gmvc - bv2 * NQ;

    #pragma unroll
    for (int t = 0; t < 4; ++t) {
        const int hh = ((n0 >> 5) + t) & 15;
        float bva = ldf(biasv, n0 + t * 32 + lr, fl);
        float bvb = ldf(biasv, n0 + t * 32 + 16 + lr, fl);
        asm volatile("" ::: "memory");
        if (s == 2) {
            #pragma unroll
            for (int i = 0; i < 4; ++i) {
                int nl = i * 16 + kc * 4;
                uint2 ua = pk4(acc[i][2*t][0] + bva, acc[i][2*t][1] + bva,
                               acc[i][2*t][2] + bva, acc[i][2*t][3] + bva);
                uint2 ub = pk4(acc[i][2*t+1][0] + bvb, acc[i][2*t+1][1] + bvb,
                               acc[i][2*t+1][2] + bvb, acc[i][2*t+1][3] + bvb);
                *(uint2*)(void*)&Tw[lr * 72 + nl]        = ua;
                *(uint2*)(void*)&Tw[(16 + lr) * 72 + nl] = ub;
            }
        } else {
            float sc = (s == 0) ? QS2 : 1.0f;
            #pragma unroll
            for (int i = 0; i < 4; ++i)
                #pragma unroll
                for (int r = 0; r < 4; ++r) {
                    int nl = i * 16 + kc * 4 + r;
                    Tw[nl * 40 + lr]      = (short)f2bf((acc[i][2*t][r]   + bva) * sc);
                    Tw[nl * 40 + 16 + lr] = (short)f2bf((acc[i][2*t+1][r] + bvb) * sc);
                }
        }
        asm volatile("" ::: "memory");
        __builtin_amdgcn_s_waitcnt(0xc07f);
        asm volatile("" ::: "memory");
        if (s == 2) {
            if (gmv < M) {
                size_t bh = (size_t)(bv2 * 16 + hh);
                #pragma unroll
                for (int i2 = 0; i2 < 8; ++i2) {
                    int d = (lane >> 4) + i2 * 4;
                    uint2 u = *(const uint2*)(const void*)&Tw[d * 72 + (lane & 15) * 4];
                    *(uint2*)(void*)(Vtw + (bh * HD + d) * VSTRIDE + nnv) = u;
                }
            }
        } else {
            if (gmr < M) {
                size_t bh = (size_t)(bq * 16 + hh);
                __hip_bfloat16* dst = (s == 0 ? Qw : Kw) + (bh * NQ + nnq) * HD;
                #pragma unroll
                for (int c = 0; c < 4; ++c) {
                    short8 u = *(const short8*)(const void*)&Tw[lane * 40 + c * 8];
                    *(short8*)(void*)(dst + c * 8) = u;
                }
            }
        }
        asm volatile("" ::: "memory");
        __builtin_amdgcn_s_waitcnt(0xc07f);
        asm volatile("" ::: "memory");
    }
}

// ----- proj GEMM: 128x128, PIPELINED K-loop (3-buf, depth-2): Out=A@Bt^T+bias
__global__ __launch_bounds__(256) void gemm_bt(
    const __hip_bfloat16* __restrict__ A,
    const __hip_bfloat16* __restrict__ Bt,
    const void* __restrict__ biasv,
    int M,
    __hip_bfloat16* __restrict__ Out,
    float* __restrict__ OutF,
    const int* __restrict__ flag) {
    __shared__ __attribute__((aligned(16))) short sStage[3 * 8192];   // 48 KB
    const int tid = threadIdx.x;
    const int lane = tid & 63;
    const int wv = tid >> 6;
    const int wr = wv >> 1, wc = wv & 1;
    const int lr = lane & 15, kc = lane >> 4;
    const int m0 = blockIdx.y * 128;
    const int n0 = blockIdx.x * 128;
    const int fl = *flag;

    auto stage = [&](int s) {
        char* bb = (char*)sStage + (s % 3) * 16384;
        const int k0 = s * 32;
        #pragma unroll
        for (int it = 0; it < 2; ++it) {
            int idx = it * 256 + tid;
            int r = idx >> 2;
            int c = idx & 3;
            int gr = m0 + r; if (gr > M - 1) gr = M - 1;
            gld_lds16(A + (size_t)gr * KDIM + k0 + c * 8, bb + idx * 16);
            gld_lds16(Bt + (size_t)(n0 + r) * KDIM + k0 + c * 8, bb + 8192 + idx * 16);
        }
    };

    f32x4 acc[4][4] = {};
    stage(0);
    stage(1);

    for (int ks = 0; ks < 16; ++ks) {
        asm volatile("" ::: "memory");
        if (ks < 15) __builtin_amdgcn_s_waitcnt(0x0074);  // vmcnt(4) lgkm(0)
        else         __builtin_amdgcn_s_waitcnt(0x0070);
        __builtin_amdgcn_s_barrier();
        asm volatile("" ::: "memory");
        if (ks + 2 < 16) stage(ks + 2);

        const char* bb = (const char*)sStage + (ks % 3) * 16384;
        const short* cA = (const short*)bb;
        const short* cB = (const short*)(bb + 8192);
        short8 af[4], bfr[4];
        #pragma unroll
        for (int t = 0; t < 4; ++t)
            af[t] = *(const short8*)&cA[(wr * 64 + t * 16 + lr) * 32 + kc * 8];
        #pragma unroll
        for (int t = 0; t < 4; ++t)
            bfr[t] = *(const short8*)&cB[(wc * 64 + t * 16 + lr) * 32 + kc * 8];
        #pragma unroll
        for (int i = 0; i < 4; ++i)
            #pragma unroll
            for (int j = 0; j < 4; ++j)
                acc[i][j] = __builtin_amdgcn_mfma_f32_16x16x32_bf16(af[i], bfr[j], acc[i][j], 0, 0, 0);
    }

    #pragma unroll
    for (int i = 0; i < 4; ++i) {
        #pragma unroll
        for (int j = 0; j < 4; ++j) {
            int gn = n0 + wc * 64 + j * 16 + lr;
            float bv = ldf(biasv, gn, fl);
            #pragma unroll
            for (int r = 0; r < 4; ++r) {
                int gm = m0 + wr * 64 + i * 16 + kc * 4 + r;
                if (gm < M) {
                    float v = acc[i][j][r] + bv;
                    if (fl) OutF[(size_t)gm * CD + gn] = v;
                    else    Out[(size_t)gm * CD + gn] = __hip_bfloat16(v);
                }
            }
        }
    }
}

// ---- fused attention v9: WG-shared K/V staging in [unit][row] layout --------
// Stage lane mapping transposed so LDS reads are stride-4-dword (2-way banks,
// free) instead of stride-16 (8-way). Bias decode = HW v_cvt_pk_f32_bf8.
__global__ __launch_bounds__(256) void attn_k(
    const __hip_bfloat16* __restrict__ Qw,
    const __hip_bfloat16* __restrict__ Kw,
    const __hip_bfloat16* __restrict__ Vtw,
    const unsigned int* __restrict__ biasF,
    __hip_bfloat16* __restrict__ AO) {
    __shared__ __attribute__((aligned(16))) short sStage[3 * 2048];        // 12 KB
    __shared__ __attribute__((aligned(16))) __hip_bfloat16 Pt[4][32 * PTS]; // 10 KB

    const int tid = threadIdx.x;
    const int wv = tid >> 6;
    const int pair = blockIdx.x * 4 + wv;    // 0..23 exactly
    const int bh = blockIdx.y;               // b*16 + h
    const int hh = bh & 15;
    const int b = bh >> 4;
    const int q0 = pair * 32;
    const int lane = tid & 63;
    const int lr = lane & 15, kc = lane >> 4;

    const __hip_bfloat16* Qb = Qw + (size_t)bh * NQ * HD;
    const __hip_bfloat16* Kb = Kw + (size_t)bh * NQ * HD;
    const __hip_bfloat16* Vb = Vtw + (size_t)bh * HD * VSTRIDE;
    __hip_bfloat16* Pw = &Pt[wv][0];

    short8 qfA = *(const short8*)(const void*)(Qb + (q0 + lr) * HD + kc * 8);
    short8 qfB = *(const short8*)(const void*)(Qb + (q0 + 16 + lr) * HD + kc * 8);

    short8 onesf;
    {
        short s1 = (lr == 0) ? (short)0x3F80 : (short)0;
        #pragma unroll
        for (int j = 0; j < 8; ++j) onesf[j] = s1;
    }

    const unsigned int* bt0 = biasF + (size_t)(hh * NQT + 2 * pair) * 48 * 64 + lane;
    const unsigned int* bt1 = bt0 + 48 * 64;

    unsigned int brA0[2], brA1[2], brB0[2], brB1[2];
    brA0[0] = bt0[0];  brA1[0] = bt0[64];
    brB0[0] = bt1[0];  brB1[0] = bt1[64];

    // staging: [unit 4][row 32] blocks (transposed lane mapping). K: lanes
    // 0..127 (row=l&31, unit=l>>5); V: lanes 128..255 (d=u&31, unit=u>>5).
    {
        const void* src;
        if (tid < 128) src = Kb + (tid & 31) * HD + (tid >> 5) * 8;
        else { int u = tid - 128; src = Vb + (u & 31) * VSTRIDE + ((u >> 5) & 3) * 8; }
        gld_lds16(src, (char*)sStage + tid * 16);
    }
    asm volatile("" ::: "memory");

    f32x4 oa0 = {}, ob0 = {}, ol0 = {};
    f32x4 oa1 = {}, ob1 = {}, ol1 = {};

    #pragma unroll
    for (int ks = 0; ks < 24; ++ks) {
        const int cur = ks & 1, nxt = cur ^ 1;
        if (ks < 23) {
            brA0[nxt] = bt0[(2 * ks + 2) * 64];
            brA1[nxt] = bt0[(2 * ks + 3) * 64];
            brB0[nxt] = bt1[(2 * ks + 2) * 64];
            brB1[nxt] = bt1[(2 * ks + 3) * 64];
            const int k0n = (ks + 1) * 32;
            const int nb = ((ks + 1) % 3) * 4096;
            const void* src;
            if (tid < 128) src = Kb + (k0n + (tid & 31)) * HD + (tid >> 5) * 8;
            else { int u = tid - 128; src = Vb + (u & 31) * VSTRIDE + k0n + ((u >> 5) & 3) * 8; }
            gld_lds16(src, (char*)sStage + nb + tid * 16);
        }
        asm volatile("" ::: "memory");
        if (ks < 23) __builtin_amdgcn_s_waitcnt(0x0F75);   // vmcnt(5)
        else         __builtin_amdgcn_s_waitcnt(0x0F70);   // vmcnt(0)
        __builtin_amdgcn_s_barrier();
        asm volatile("" ::: "memory");

        const short* sK = (const short*)((const char*)sStage + (ks % 3) * 4096);
        const short* sV = sK + 1024;
        // [unit][row]: addr = kc*256 + row*8 shorts -> 2-way banks (free)
        short8 kf0 = *(const short8*)&sK[kc * 256 + lr * 8];
        short8 kf1 = *(const short8*)&sK[kc * 256 + (16 + lr) * 8];
        short8 vf0 = *(const short8*)&sV[kc * 256 + lr * 8];
        short8 vf1 = *(const short8*)&sV[kc * 256 + (16 + lr) * 8];

        f32x4 c0 = bias4f8(brA0[cur]);
        f32x4 c1 = bias4f8(brA1[cur]);
        f32x4 c2 = bias4f8(brB0[cur]);
        f32x4 c3 = bias4f8(brB1[cur]);

        c0 = __builtin_amdgcn_mfma_f32_16x16x32_bf16(kf0, qfA, c0, 0, 0, 0);
        c1 = __builtin_amdgcn_mfma_f32_16x16x32_bf16(kf1, qfA, c1, 0, 0, 0);
        c2 = __builtin_amdgcn_mfma_f32_16x16x32_bf16(kf0, qfB, c2, 0, 0, 0);
        c3 = __builtin_amdgcn_mfma_f32_16x16x32_bf16(kf1, qfB, c3, 0, 0, 0);

        #pragma unroll
        for (int r = 0; r < 4; ++r) {
            c0[r] = fexp2(c0[r]); c1[r] = fexp2(c1[r]);
            c2[r] = fexp2(c2[r]); c3[r] = fexp2(c3[r]);
        }
        pkstore(Pw + lr * PTS + kc * 4, c0);
        pkstore(Pw + lr * PTS + 16 + kc * 4, c1);
        pkstore(Pw + (16 + lr) * PTS + kc * 4, c2);
        pkstore(Pw + (16 + lr) * PTS + 16 + kc * 4, c3);
        asm volatile("" ::: "memory");
        __builtin_amdgcn_s_waitcnt(0xc07f);   // lgkmcnt(0)
        asm volatile("" ::: "memory");

        short8 pfA = *(const short8*)(const void*)(Pw + lr * PTS + kc * 8);
        short8 pfB = *(const short8*)(const void*)(Pw + (16 + lr) * PTS + kc * 8);

        oa0 = __builtin_amdgcn_mfma_f32_16x16x32_bf16(pfA, vf0, oa0, 0, 0, 0);
        ob0 = __builtin_amdgcn_mfma_f32_16x16x32_bf16(pfA, vf1, ob0, 0, 0, 0);
        ol0 = __builtin_amdgcn_mfma_f32_16x16x32_bf16(pfA, onesf, ol0, 0, 0, 0);
        oa1 = __builtin_amdgcn_mfma_f32_16x16x32_bf16(pfB, vf0, oa1, 0, 0, 0);
        ob1 = __builtin_amdgcn_mfma_f32_16x16x32_bf16(pfB, vf1, ob1, 0, 0, 0);
        ol1 = __builtin_amdgcn_mfma_f32_16x16x32_bf16(pfB, onesf, ol1, 0, 0, 0);
    }

    #pragma unroll
    for (int r = 0; r < 4; ++r) {
        int row = kc * 4 + r;
        float lA = __shfl(ol0[r], lane & 48);
        float lB = __shfl(ol1[r], lane & 48);
        float liA = 1.0f / lA, liB = 1.0f / lB;
        int orA = q0 + row, orB = q0 + 16 + row;
        if (orA < NQ) {
            size_t base = ((size_t)b * NQ + orA) * CD + hh * HD;
            AO[base + lr]      = __hip_bfloat16(oa0[r] * liA);
            AO[base + 16 + lr] = __hip_bfloat16(ob0[r] * liA);
        }
        if (orB < NQ) {
            size_t base = ((size_t)b * NQ + orB) * CD + hh * HD;
            AO[base + lr]      = __hip_bfloat16(oa1[r] * liB);
            AO[base + 16 + lr] = __hip_bfloat16(ob1[r] * liB);
        }
    }
}

extern "C" void kernel_launch(void* const* d_in, const int* in_sizes, int n_in,
                              void* d_out, int out_size, void* d_ws, size_t ws_size,
                              hipStream_t stream) {
    char* ws = (char*)d_ws;
    size_t off = 0;
    auto carve = [&](size_t bytes) {
        char* p = ws + off;
        off += (bytes + 255) & ~(size_t)255;
        return p;
    };
    int* flagp = (int*)carve(256);
    __hip_bfloat16* Qw    = (__hip_bfloat16*)carve((size_t)256 * NQ * HD * 2);
    __hip_bfloat16* Kw    = (__hip_bfloat16*)carve((size_t)256 * NQ * HD * 2);
    __hip_bfloat16* Vtw   = (__hip_bfloat16*)carve((size_t)256 * HD * VSTRIDE * 2);
    __hip_bfloat16* WqT   = (__hip_bfloat16*)carve((size_t)1536 * 512 * 2);
    __hip_bfloat16* WpT   = (__hip_bfloat16*)carve((size_t)512 * 512 * 2);
    unsigned int*   biasF = (unsigned int*)carve((size_t)16 * NQT * 48 * 64 * 4);
    __hip_bfloat16* Xb    = (__hip_bfloat16*)carve((size_t)MROWS * CD * 2);
    __hip_bfloat16* AO    = Xb;   // attn output overwrites x-staging (dead after qkv gemm)
    (void)ws_size; (void)in_sizes; (void)n_in; (void)out_size;

    sniff_k<<<dim3(1), dim3(64), 0, stream>>>((const unsigned int*)d_in[1], flagp);
    prep_k<<<dim3(PREP_CONV + PREP_TA + PREP_TB + PREP_BIAS), dim3(256), 0, stream>>>(
        d_in[0], (ushort4*)Xb, d_in[1], WqT, d_in[3], WpT,
        d_in[5], d_in[6], d_in[7], d_in[8], d_in[9], d_in[10], biasF, flagp);
    gemm_qkv<<<dim3(12, 47), dim3(256), 0, stream>>>(Xb, WqT, d_in[2],
        Qw, Kw, Vtw, flagp);
    attn_k<<<dim3(6, 256), dim3(256), 0, stream>>>(Qw, Kw, Vtw, biasF, AO);
    gemm_bt<<<dim3(4, 93), dim3(256), 0, stream>>>(AO, WpT, d_in[4], MROWS,
        (__hip_bfloat16*)d_out, (float*)d_out, flagp);
}